// Round 3
// baseline (635.267 us; speedup 1.0000x reference)
//
#include <hip/hip_runtime.h>
#include <stdint.h>

#define B 16
#define D 2
#define NN 100
#define N2 50
#define NA 102
#define H 128
#define HE 64
#define L 3
#define SLOPE 0.2f
#define EPS 1e-5f

#define NAE (NA*NA)          // 10404
#define EN (B*NAE)           // 166464 edge rows per graph
#define R1 (B*NA)            // 1632
#define R2 (B*N2)            // 800
#define RV (R1 + 2*R2)       // 3232 rows in V/AB/XO per graph
#define NC 202               // per-batch row count in the reference's scrambled reshape

// ---- workspace layout (float offsets) ----
#define ACC_MOM   0            // 2 graphs * 5 moments
#define ACC_NODE  16           // 3 segs * (128 sum + 128 sumsq)
#define ACC_FF    1024         // 2 graphs * (128 sum + 128 sumsq)
#define OFF_ST    2048         // 2 graphs * (64 e0s + 64 e1s + 64 t)
#define OFF_X0    2560
#define OFF_V     (OFF_X0 + R1*H)
#define OFF_AB    (OFF_V + 2*RV*H)
#define OFF_XO    (OFF_AB + 2*RV*2*H)
#define OFF_XF    (OFF_XO + 2*RV*H)
#define OFF_H1    (OFF_XF + 2*R1*H)
#define OFF_Z     (OFF_H1 + 2*R1*H)

// decode a V/AB/XO row index -> (batch, node)  [flat concat order: X1 | X2 | X3]
__device__ __forceinline__ void decode_vrow(int ridx, int& b, int& node) {
    if (ridx < R1) { b = ridx / NA; node = ridx % NA; }
    else if (ridx < R1 + R2) { int p = ridx - R1; b = p / N2; node = D + p % N2; }
    else { int p = ridx - R1 - R2; b = p / N2; node = D + N2 + p % N2; }
}
// decode node-init virtual row -> (batch, node); segment layout 32 dep / 800 pk / 800 dl
__device__ __forceinline__ void decode_nrow(int vr, int& b, int& node) {
    if (vr < 32) { b = vr >> 1; node = vr & 1; }
    else if (vr < 832) { int p = vr - 32; b = p / N2; node = D + p % N2; }
    else { int p = vr - 832; b = p / N2; node = D + N2 + p % N2; }
}
// conv output per the reference's EXACT semantics:
// Xc[b,q] = flat[b*202+q] where flat = [X1(1632 rows); X2(800); X3(800)]
// out[b,n] = Xc[b,n] + (n>=D ? Xc[b,n+100] : 0)
// Our XO buffer rows are stored precisely in flat order, so:
__device__ __forceinline__ float combined(const float* __restrict__ XO, int b, int node, int k) {
    float v = XO[(b*NC + node)*H + k];
    if (node >= D) v += XO[(b*NC + node + 100)*H + k];
    return v;
}

// ---- zero the accumulator region (graph-capture-safe) ----
__global__ __launch_bounds__(256) void k_zero(float* __restrict__ ws) {
    for (int i = threadIdx.x; i < 2048; i += 256) ws[i] = 0.0f;
}

// ---- edge-attr moments: 5 scalar sums per graph ----
__global__ __launch_bounds__(256) void k_moments(const float* __restrict__ ea_d,
                                                 const float* __restrict__ ea_r,
                                                 float* __restrict__ ws) {
    int g = blockIdx.x >> 7;       // 128 blocks per graph
    int bb = blockIdx.x & 127;
    const float2* ea = (const float2*)(g ? ea_r : ea_d);
    float s0 = 0, s1 = 0, s00 = 0, s11 = 0, s01 = 0;
    for (int idx = bb*256 + threadIdx.x; idx < EN; idx += 128*256) {
        float2 v = ea[idx];
        s0 += v.x; s1 += v.y; s00 += v.x*v.x; s11 += v.y*v.y; s01 += v.x*v.y;
    }
    __shared__ float sd[256];
    float vals[5] = {s0, s1, s00, s11, s01};
    for (int q = 0; q < 5; q++) {
        sd[threadIdx.x] = vals[q];
        __syncthreads();
        for (int off = 128; off > 0; off >>= 1) {
            if (threadIdx.x < off) sd[threadIdx.x] += sd[threadIdx.x + off];
            __syncthreads();
        }
        if (threadIdx.x == 0) atomicAdd(&ws[ACC_MOM + g*5 + q], sd[0]);
        __syncthreads();
    }
}

// ---- fold edge BN into per-channel affine: e0s, e1s, t ----
__global__ __launch_bounds__(128) void k_st(const float* __restrict__ W3, const float* __restrict__ W4,
                                            const float* __restrict__ b3g, const float* __restrict__ b3b,
                                            const float* __restrict__ b4g, const float* __restrict__ b4b,
                                            float* __restrict__ ws) {
    int g = threadIdx.x >> 6, c = threadIdx.x & 63;
    const float* W  = g ? W4 : W3;
    const float* gv = g ? b4g : b3g;
    const float* bv = g ? b4b : b3b;
    float Nr = (float)EN;
    float S0 = ws[ACC_MOM + g*5 + 0], S1 = ws[ACC_MOM + g*5 + 1];
    float S00 = ws[ACC_MOM + g*5 + 2], S11 = ws[ACC_MOM + g*5 + 3], S01 = ws[ACC_MOM + g*5 + 4];
    float w0 = W[c], w1 = W[64 + c];
    float m = (S0*w0 + S1*w1) / Nr;
    float E2 = (S00*w0*w0 + 2.0f*S01*w0*w1 + S11*w1*w1) / Nr;
    float var = E2 - m*m;
    float s = gv[c] * rsqrtf(var + EPS);
    float t = bv[c] - m*s;
    ws[OFF_ST + g*192 + c]        = w0 * s;
    ws[OFF_ST + g*192 + 64 + c]   = w1 * s;
    ws[OFF_ST + g*192 + 128 + c]  = t;
}

// ---- initial node embeddings: linear + stat accumulation ----
__global__ __launch_bounds__(128) void k_nodeinit(const float* __restrict__ x, const float* __restrict__ dm,
                                                  const float* __restrict__ tw,
                                                  const float* __restrict__ W0, const float* __restrict__ W1,
                                                  const float* __restrict__ W2, float* __restrict__ ws) {
    int c = threadIdx.x, bx = blockIdx.x;
    int seg = (bx < 2) ? 0 : (bx < 52 ? 1 : 2);
    const float* W = seg == 0 ? W0 : (seg == 1 ? W1 : W2);
    int nf = seg == 1 ? 10 : 5;
    float w[10];
    for (int f = 0; f < nf; f++) w[f] = W[f*H + c];
    float* x0 = ws + OFF_X0;
    float ls = 0, lss = 0;
    for (int r = 0; r < 16; r++) {
        int vr = bx*16 + r;
        int b, node; decode_nrow(vr, b, node);
        int row = b*NA + node;
        float y = x[row*2]*w[0] + x[row*2+1]*w[1] + dm[row]*w[2]
                + tw[row*2]*w[3] + tw[row*2+1]*w[4];
        if (seg == 1) {
            int r2 = row + N2;
            y += x[r2*2]*w[5] + x[r2*2+1]*w[6] + dm[r2]*w[7]
               + tw[r2*2]*w[8] + tw[r2*2+1]*w[9];
        }
        x0[row*H + c] = y;
        ls += y; lss += y*y;
    }
    atomicAdd(&ws[ACC_NODE + seg*256 + c], ls);
    atomicAdd(&ws[ACC_NODE + seg*256 + 128 + c], lss);
}

__global__ __launch_bounds__(128) void k_nodenorm(const float* __restrict__ b0g, const float* __restrict__ b0b,
                                                  const float* __restrict__ b1g, const float* __restrict__ b1b,
                                                  const float* __restrict__ b2g, const float* __restrict__ b2b,
                                                  float* __restrict__ ws) {
    int c = threadIdx.x, bx = blockIdx.x;
    int seg = (bx < 2) ? 0 : (bx < 52 ? 1 : 2);
    float cnt = seg == 0 ? 32.0f : 800.0f;
    float m = ws[ACC_NODE + seg*256 + c] / cnt;
    float v = ws[ACC_NODE + seg*256 + 128 + c] / cnt - m*m;
    const float* gp = seg == 0 ? b0g : (seg == 1 ? b1g : b2g);
    const float* bp = seg == 0 ? b0b : (seg == 1 ? b1b : b2b);
    float sc = gp[c] * rsqrtf(v + EPS);
    float sh = bp[c] - m*sc;
    float* x0 = ws + OFF_X0;
    for (int r = 0; r < 16; r++) {
        int vr = bx*16 + r;
        int b, node; decode_nrow(vr, b, node);
        int row = b*NA + node;
        x0[row*H + c] = x0[row*H + c]*sc + sh;
    }
}

// ---- GEMM1: combined x -> V = x @ Wvl{a,p,d}[l]  (2*3232 rows x 128) ----
__global__ __launch_bounds__(256) void k_gemm1(const float* __restrict__ Wvla, const float* __restrict__ Wvlp,
                                               const float* __restrict__ Wvld, int layer, float* __restrict__ ws) {
    __shared__ float xs[16][H];
    int g = blockIdx.x / 202, tb = blockIdx.x % 202;
    int rowbase = tb * 16;
    const float* x0 = ws + OFF_X0;
    const float* XO = ws + OFF_XO + g*RV*H;
    for (int e = 0; e < 8; e++) {
        int lin = threadIdx.x + e*256;
        int r = lin >> 7, k = lin & 127;
        int b, node; decode_vrow(rowbase + r, b, node);
        xs[r][k] = (layer == 0) ? x0[(b*NA + node)*H + k] : combined(XO, b, node, k);
    }
    __syncthreads();
    int seg = rowbase < R1 ? 0 : (rowbase < R1 + R2 ? 1 : 2);
    const float* W = (seg == 0 ? Wvla : (seg == 1 ? Wvlp : Wvld)) + layer*H*H;
    int col = threadIdx.x & 127, half = threadIdx.x >> 7;
    float acc[8] = {0,0,0,0,0,0,0,0};
    for (int k = 0; k < H; k++) {
        float w = W[k*H + col];
        #pragma unroll
        for (int rr = 0; rr < 8; rr++) acc[rr] += xs[half + rr*2][k] * w;
    }
    float* V = ws + OFF_V + g*RV*H;
    #pragma unroll
    for (int rr = 0; rr < 8; rr++) V[(rowbase + half + rr*2)*H + col] = acc[rr];
}

// ---- GEMM2: V -> AB = xk @ [wi | wj]  (2*3232 rows x 256) ----
__global__ __launch_bounds__(256) void k_gemm2(const float* __restrict__ Wga, const float* __restrict__ Wgp,
                                               const float* __restrict__ Wgd, int layer, float* __restrict__ ws) {
    __shared__ float xs[16][H];
    int g = blockIdx.x / 202, tb = blockIdx.x % 202;
    int rowbase = tb * 16;
    const float* V = ws + OFF_V + g*RV*H;
    for (int e = 0; e < 8; e++) {
        int lin = threadIdx.x + e*256;
        int r = lin >> 7, k = lin & 127;
        xs[r][k] = V[(rowbase + r)*H + k];
    }
    __syncthreads();
    int seg = rowbase < R1 ? 0 : (rowbase < R1 + R2 ? 1 : 2);
    const float* Wg = (seg == 0 ? Wga : (seg == 1 ? Wgp : Wgd)) + layer*320*H;
    int c = threadIdx.x;
    const float* wb = Wg + ((c >> 7) * H) * H + (c & 127);
    float acc[16];
    #pragma unroll
    for (int rr = 0; rr < 16; rr++) acc[rr] = 0.0f;
    for (int k = 0; k < H; k++) {
        float w = wb[k*H];
        #pragma unroll
        for (int rr = 0; rr < 16; rr++) acc[rr] += xs[rr][k] * w;
    }
    float* AB = ws + OFF_AB + g*RV*2*H;
    #pragma unroll
    for (int rr = 0; rr < 16; rr++) AB[(rowbase + rr)*256 + c] = acc[rr];
}

// ---- fused attention (per-channel masked softmax over i) ----
__global__ __launch_bounds__(128) void k_attn(const float* __restrict__ Wga, const float* __restrict__ Wgp,
                                              const float* __restrict__ Wgd,
                                              const float* __restrict__ ea_d, const float* __restrict__ ea_r,
                                              const int* __restrict__ mask_d, const int* __restrict__ mask_r,
                                              int layer, float* __restrict__ ws) {
    int h = threadIdx.x;
    int g = blockIdx.x / RV;
    int idx = blockIdx.x % RV;
    int seg, b, j, n, o, base;
    if (idx < R1) { seg = 0; b = idx / NA; j = idx % NA; n = NA; o = 0; base = 0; }
    else if (idx < R1 + R2) { seg = 1; int p = idx - R1; b = p / N2; j = p % N2; n = N2; o = D; base = R1; }
    else { seg = 2; int p = idx - R1 - R2; b = p / N2; j = p % N2; n = N2; o = D + N2; base = R1 + R2; }
    const float* Wg = (seg == 0 ? Wga : (seg == 1 ? Wgp : Wgd)) + layer*320*H;
    const float* st = ws + OFF_ST + g*192;
    const float2* ea = (const float2*)(g ? ea_r : ea_d);
    const int* mask = g ? mask_r : mask_d;
    const float* V  = ws + OFF_V  + g*RV*H   + base*H;
    const float* AB = ws + OFF_AB + g*RV*2*H + base*2*H;

    float P = 0, Q = 0, R = 0;
    for (int cc = 0; cc < HE; cc++) {
        float w = Wg[(2*H + cc)*H + h];
        P += st[cc] * w; Q += st[64 + cc] * w; R += st[128 + cc] * w;
    }
    float Aj = AB[(b*n + j)*256 + h];
    int mbase = b*NAE + o*NA + (o + j);

    float mx = -INFINITY;
    for (int i = 0; i < n; i++) {
        if (mask[mbase + i*NA]) {
            float2 ev = ea[mbase + i*NA];
            float Bi = AB[(b*n + i)*256 + 128 + h];
            float t = Aj + Bi + ev.x*P + ev.y*Q + R;
            t = t >= 0.0f ? t : SLOPE*t;
            mx = fmaxf(mx, t);
        }
    }
    float l = 0, acc = 0;
    for (int i = 0; i < n; i++) {
        if (mask[mbase + i*NA]) {
            float2 ev = ea[mbase + i*NA];
            float Bi = AB[(b*n + i)*256 + 128 + h];
            float t = Aj + Bi + ev.x*P + ev.y*Q + R;
            t = t >= 0.0f ? t : SLOPE*t;
            float p = __expf(t - mx);
            l += p;
            acc += p * V[(b*n + i)*H + h];
        }
    }
    float* XO = ws + OFF_XO + g*RV*H + base*H;
    XO[(b*n + j)*H + h] = acc / l;
}

// ---- feed-forward stage 1: xf = combined (scrambled semantics), H1 = relu(xf@W1+b1) ----
__global__ __launch_bounds__(256) void k_f1(const float* __restrict__ ffw1, const float* __restrict__ ffb1,
                                            float* __restrict__ ws) {
    __shared__ float xs[16][H];
    int g = blockIdx.x / 102, tb = blockIdx.x % 102;
    int rowbase = tb * 16;
    const float* XO = ws + OFF_XO + g*RV*H;
    float* XF = ws + OFF_XF + g*R1*H;
    for (int e = 0; e < 8; e++) {
        int lin = threadIdx.x + e*256;
        int r = lin >> 7, k = lin & 127;
        int ridx = rowbase + r;
        int b = ridx / NA, node = ridx % NA;
        float val = combined(XO, b, node, k);
        xs[r][k] = val;
        XF[ridx*H + k] = val;
    }
    __syncthreads();
    int col = threadIdx.x & 127, half = threadIdx.x >> 7;
    float acc[8] = {0,0,0,0,0,0,0,0};
    for (int k = 0; k < H; k++) {
        float w = ffw1[k*H + col];
        #pragma unroll
        for (int rr = 0; rr < 8; rr++) acc[rr] += xs[half + rr*2][k] * w;
    }
    float bias = ffb1[col];
    float* H1 = ws + OFF_H1 + g*R1*H;
    #pragma unroll
    for (int rr = 0; rr < 8; rr++) {
        float hv = acc[rr] + bias;
        H1[(rowbase + half + rr*2)*H + col] = hv > 0.0f ? hv : 0.0f;
    }
}

// ---- feed-forward stage 2: Z = XF + H1@W2 + b2, accumulate BN stats ----
__global__ __launch_bounds__(256) void k_f2(const float* __restrict__ ffw2, const float* __restrict__ ffb2,
                                            float* __restrict__ ws) {
    __shared__ float xs[16][H];
    int g = blockIdx.x / 102, tb = blockIdx.x % 102;
    int rowbase = tb * 16;
    const float* H1 = ws + OFF_H1 + g*R1*H;
    for (int e = 0; e < 8; e++) {
        int lin = threadIdx.x + e*256;
        int r = lin >> 7, k = lin & 127;
        xs[r][k] = H1[(rowbase + r)*H + k];
    }
    __syncthreads();
    int col = threadIdx.x & 127, half = threadIdx.x >> 7;
    float acc[8] = {0,0,0,0,0,0,0,0};
    for (int k = 0; k < H; k++) {
        float w = ffw2[k*H + col];
        #pragma unroll
        for (int rr = 0; rr < 8; rr++) acc[rr] += xs[half + rr*2][k] * w;
    }
    float bias = ffb2[col];
    const float* XF = ws + OFF_XF + g*R1*H;
    float* Z = ws + OFF_Z + g*R1*H;
    float ls = 0, lss = 0;
    #pragma unroll
    for (int rr = 0; rr < 8; rr++) {
        int row = rowbase + half + rr*2;
        float z = acc[rr] + bias + XF[row*H + col];
        Z[row*H + col] = z;
        ls += z; lss += z*z;
    }
    atomicAdd(&ws[ACC_FF + g*256 + col], ls);
    atomicAdd(&ws[ACC_FF + g*256 + 128 + col], lss);
}

// ---- final BN + output ----
__global__ __launch_bounds__(256) void k_f3(const float* __restrict__ bng, const float* __restrict__ bnb,
                                            float* __restrict__ ws, float* __restrict__ out) {
    int eidx = blockIdx.x * 256 + threadIdx.x;   // 2*R1*H = 417792 total
    int g = eidx / (R1*H);
    int rem = eidx % (R1*H);
    int c = rem & 127;
    float m = ws[ACC_FF + g*256 + c] / 1632.0f;
    float v = ws[ACC_FF + g*256 + 128 + c] / 1632.0f - m*m;
    float sc = bng[c] * rsqrtf(v + EPS);
    float sh = bnb[c] - m*sc;
    out[eidx] = ws[OFF_Z + eidx] * sc + sh;
}

extern "C" void kernel_launch(void* const* d_in, const int* in_sizes, int n_in,
                              void* d_out, int out_size, void* d_ws, size_t ws_size,
                              hipStream_t stream) {
    const float* x    = (const float*)d_in[0];
    const float* dm   = (const float*)d_in[1];
    const float* tw   = (const float*)d_in[2];
    const float* ead  = (const float*)d_in[3];
    const float* ear  = (const float*)d_in[4];
    const float* W0   = (const float*)d_in[5];
    const float* W1   = (const float*)d_in[6];
    const float* W2   = (const float*)d_in[7];
    const float* W3   = (const float*)d_in[8];
    const float* W4   = (const float*)d_in[9];
    const float* b0g  = (const float*)d_in[10];
    const float* b0b  = (const float*)d_in[11];
    const float* b1g  = (const float*)d_in[12];
    const float* b1b  = (const float*)d_in[13];
    const float* b2g  = (const float*)d_in[14];
    const float* b2b  = (const float*)d_in[15];
    const float* b3g  = (const float*)d_in[16];
    const float* b3b  = (const float*)d_in[17];
    const float* b4g  = (const float*)d_in[18];
    const float* b4b  = (const float*)d_in[19];
    const float* ffw1 = (const float*)d_in[20];
    const float* ffb1 = (const float*)d_in[21];
    const float* ffw2 = (const float*)d_in[22];
    const float* ffb2 = (const float*)d_in[23];
    const float* bng  = (const float*)d_in[24];
    const float* bnb  = (const float*)d_in[25];
    const float* Wvla = (const float*)d_in[26];
    const float* Wvlp = (const float*)d_in[27];
    const float* Wvld = (const float*)d_in[28];
    const float* Wga  = (const float*)d_in[29];
    const float* Wgp  = (const float*)d_in[30];
    const float* Wgd  = (const float*)d_in[31];
    // d_in[32] = edge_index (unused by forward)
    const int* mask_d = (const int*)d_in[33];
    const int* mask_r = (const int*)d_in[34];
    float* ws = (float*)d_ws;
    float* out = (float*)d_out;

    k_zero    <<<1, 256, 0, stream>>>(ws);
    k_moments <<<256, 256, 0, stream>>>(ead, ear, ws);
    k_st      <<<1, 128, 0, stream>>>(W3, W4, b3g, b3b, b4g, b4b, ws);
    k_nodeinit<<<102, 128, 0, stream>>>(x, dm, tw, W0, W1, W2, ws);
    k_nodenorm<<<102, 128, 0, stream>>>(b0g, b0b, b1g, b1b, b2g, b2b, ws);
    for (int l = 0; l < L; l++) {
        k_gemm1<<<404, 256, 0, stream>>>(Wvla, Wvlp, Wvld, l, ws);
        k_gemm2<<<404, 256, 0, stream>>>(Wga, Wgp, Wgd, l, ws);
        k_attn <<<2*RV, 128, 0, stream>>>(Wga, Wgp, Wgd, ead, ear, mask_d, mask_r, l, ws);
    }
    k_f1<<<204, 256, 0, stream>>>(ffw1, ffb1, ws);
    k_f2<<<204, 256, 0, stream>>>(ffw2, ffb2, ws);
    k_f3<<<1632, 256, 0, stream>>>(bng, bnb, ws, out);
}

// Round 4
// 451.880 us; speedup vs baseline: 1.4058x; 1.4058x over previous
//
#include <hip/hip_runtime.h>
#include <stdint.h>

#define B 16
#define D 2
#define NN 100
#define N2 50
#define NA 102
#define H 128
#define HE 64
#define L 3
#define SLOPE 0.2f
#define EPS 1e-5f

#define NAE (NA*NA)          // 10404
#define EN (B*NAE)           // 166464 edge rows per graph
#define R1 (B*NA)            // 1632
#define R2 (B*N2)            // 800
#define RV (R1 + 2*R2)       // 3232 rows in V/AB/XO per graph
#define NC 202               // per-batch row count in the reference's scrambled reshape
#define J 4                  // j-rows per attention block

// ---- workspace layout (float offsets) ----
#define ACC_MOM   0            // 2 graphs * 5 moments
#define ACC_NODE  16           // 3 segs * (128 sum + 128 sumsq)
#define ACC_FF    1024         // 2 graphs * (128 sum + 128 sumsq)
#define OFF_ST    2048         // 2 graphs * (64 e0s + 64 e1s + 64 t)
#define OFF_PQR   2560         // 2*3*3 * (3*128)
#define OFF_X0    9472
#define OFF_V     (OFF_X0 + R1*H)          // 218368
#define OFF_AB    (OFF_V + 2*RV*H)         // 1045760
#define OFF_XO    (OFF_AB + 2*RV*2*H)      // 2700544
#define OFF_Z     (OFF_XO + 2*RV*H)        // 3527936

// decode a V/AB/XO row index -> (batch, node)  [flat concat order: X1 | X2 | X3]
__device__ __forceinline__ void decode_vrow(int ridx, int& b, int& node) {
    if (ridx < R1) { b = ridx / NA; node = ridx % NA; }
    else if (ridx < R1 + R2) { int p = ridx - R1; b = p / N2; node = D + p % N2; }
    else { int p = ridx - R1 - R2; b = p / N2; node = D + N2 + p % N2; }
}
// decode node-init virtual row -> (batch, node); 32 dep / 800 pk / 800 dl
__device__ __forceinline__ void decode_nrow(int vr, int& b, int& node) {
    if (vr < 32) { b = vr >> 1; node = vr & 1; }
    else if (vr < 832) { int p = vr - 32; b = p / N2; node = D + p % N2; }
    else { int p = vr - 832; b = p / N2; node = D + N2 + p % N2; }
}
// conv output per the reference's EXACT (scrambled reshape) semantics:
// Xc[b,q] = flat[b*202+q], flat = [X1(1632); X2(800); X3(800)]
// out[b,n] = Xc[b,n] + (n>=D ? Xc[b,n+100] : 0)
__device__ __forceinline__ float combined(const float* __restrict__ XO, int b, int node, int k) {
    float v = XO[(b*NC + node)*H + k];
    if (node >= D) v += XO[(b*NC + node + 100)*H + k];
    return v;
}

// ---- zero the accumulator region (graph-capture-safe) ----
__global__ __launch_bounds__(256) void k_zero(float* __restrict__ ws) {
    for (int i = threadIdx.x; i < 2048; i += 256) ws[i] = 0.0f;
}

// ---- edge-attr moments: 5 scalar sums per graph ----
__global__ __launch_bounds__(256) void k_moments(const float* __restrict__ ea_d,
                                                 const float* __restrict__ ea_r,
                                                 float* __restrict__ ws) {
    int g = blockIdx.x >> 7;
    int bb = blockIdx.x & 127;
    const float2* ea = (const float2*)(g ? ea_r : ea_d);
    float s0 = 0, s1 = 0, s00 = 0, s11 = 0, s01 = 0;
    for (int idx = bb*256 + threadIdx.x; idx < EN; idx += 128*256) {
        float2 v = ea[idx];
        s0 += v.x; s1 += v.y; s00 += v.x*v.x; s11 += v.y*v.y; s01 += v.x*v.y;
    }
    __shared__ float sd[256];
    float vals[5] = {s0, s1, s00, s11, s01};
    for (int q = 0; q < 5; q++) {
        sd[threadIdx.x] = vals[q];
        __syncthreads();
        for (int off = 128; off > 0; off >>= 1) {
            if (threadIdx.x < off) sd[threadIdx.x] += sd[threadIdx.x + off];
            __syncthreads();
        }
        if (threadIdx.x == 0) atomicAdd(&ws[ACC_MOM + g*5 + q], sd[0]);
        __syncthreads();
    }
}

// ---- fold edge BN into per-channel affine: e0s, e1s, t ----
__global__ __launch_bounds__(128) void k_st(const float* __restrict__ W3, const float* __restrict__ W4,
                                            const float* __restrict__ b3g, const float* __restrict__ b3b,
                                            const float* __restrict__ b4g, const float* __restrict__ b4b,
                                            float* __restrict__ ws) {
    int g = threadIdx.x >> 6, c = threadIdx.x & 63;
    const float* W  = g ? W4 : W3;
    const float* gv = g ? b4g : b3g;
    const float* bv = g ? b4b : b3b;
    float Nr = (float)EN;
    float S0 = ws[ACC_MOM + g*5 + 0], S1 = ws[ACC_MOM + g*5 + 1];
    float S00 = ws[ACC_MOM + g*5 + 2], S11 = ws[ACC_MOM + g*5 + 3], S01 = ws[ACC_MOM + g*5 + 4];
    float w0 = W[c], w1 = W[64 + c];
    float m = (S0*w0 + S1*w1) / Nr;
    float E2 = (S00*w0*w0 + 2.0f*S01*w0*w1 + S11*w1*w1) / Nr;
    float var = E2 - m*m;
    float s = gv[c] * rsqrtf(var + EPS);
    float t = bv[c] - m*s;
    ws[OFF_ST + g*192 + c]        = w0 * s;
    ws[OFF_ST + g*192 + 64 + c]   = w1 * s;
    ws[OFF_ST + g*192 + 128 + c]  = t;
}

// ---- precompute P/Q/R per (g,seg,layer,h): folds edge-affine through we ----
__global__ __launch_bounds__(128) void k_pqr(const float* __restrict__ Wga, const float* __restrict__ Wgp,
                                             const float* __restrict__ Wgd, float* __restrict__ ws) {
    int bx = blockIdx.x;           // 18 = 2 graphs * 3 segs * 3 layers
    int g = bx / 9, rem = bx % 9, seg = rem / 3, l = rem % 3;
    int h = threadIdx.x;
    const float* Wg = (seg == 0 ? Wga : (seg == 1 ? Wgp : Wgd)) + l*320*H;
    const float* st = ws + OFF_ST + g*192;
    float P = 0, Q = 0, Rr = 0;
    for (int cc = 0; cc < HE; cc++) {
        float w = Wg[(2*H + cc)*H + h];
        P += st[cc]*w; Q += st[64 + cc]*w; Rr += st[128 + cc]*w;
    }
    float* o = ws + OFF_PQR + ((g*3 + seg)*3 + l)*384;
    o[h] = P; o[128 + h] = Q; o[256 + h] = Rr;
}

// ---- initial node embeddings: linear + stat accumulation ----
__global__ __launch_bounds__(128) void k_nodeinit(const float* __restrict__ x, const float* __restrict__ dm,
                                                  const float* __restrict__ tw,
                                                  const float* __restrict__ W0, const float* __restrict__ W1,
                                                  const float* __restrict__ W2, float* __restrict__ ws) {
    int c = threadIdx.x, bx = blockIdx.x;
    int seg = (bx < 2) ? 0 : (bx < 52 ? 1 : 2);
    const float* W = seg == 0 ? W0 : (seg == 1 ? W1 : W2);
    int nf = seg == 1 ? 10 : 5;
    float w[10];
    for (int f = 0; f < nf; f++) w[f] = W[f*H + c];
    float* x0 = ws + OFF_X0;
    float ls = 0, lss = 0;
    for (int r = 0; r < 16; r++) {
        int vr = bx*16 + r;
        int b, node; decode_nrow(vr, b, node);
        int row = b*NA + node;
        float y = x[row*2]*w[0] + x[row*2+1]*w[1] + dm[row]*w[2]
                + tw[row*2]*w[3] + tw[row*2+1]*w[4];
        if (seg == 1) {
            int r2 = row + N2;
            y += x[r2*2]*w[5] + x[r2*2+1]*w[6] + dm[r2]*w[7]
               + tw[r2*2]*w[8] + tw[r2*2+1]*w[9];
        }
        x0[row*H + c] = y;
        ls += y; lss += y*y;
    }
    atomicAdd(&ws[ACC_NODE + seg*256 + c], ls);
    atomicAdd(&ws[ACC_NODE + seg*256 + 128 + c], lss);
}

__global__ __launch_bounds__(128) void k_nodenorm(const float* __restrict__ b0g, const float* __restrict__ b0b,
                                                  const float* __restrict__ b1g, const float* __restrict__ b1b,
                                                  const float* __restrict__ b2g, const float* __restrict__ b2b,
                                                  float* __restrict__ ws) {
    int c = threadIdx.x, bx = blockIdx.x;
    int seg = (bx < 2) ? 0 : (bx < 52 ? 1 : 2);
    float cnt = seg == 0 ? 32.0f : 800.0f;
    float m = ws[ACC_NODE + seg*256 + c] / cnt;
    float v = ws[ACC_NODE + seg*256 + 128 + c] / cnt - m*m;
    const float* gp = seg == 0 ? b0g : (seg == 1 ? b1g : b2g);
    const float* bp = seg == 0 ? b0b : (seg == 1 ? b1b : b2b);
    float sc = gp[c] * rsqrtf(v + EPS);
    float sh = bp[c] - m*sc;
    float* x0 = ws + OFF_X0;
    for (int r = 0; r < 16; r++) {
        int vr = bx*16 + r;
        int b, node; decode_nrow(vr, b, node);
        int row = b*NA + node;
        x0[row*H + c] = x0[row*H + c]*sc + sh;
    }
}

// ---- fused GEMM: x->V (Wvl) then V->AB ([wi|wj]) per 16-row tile ----
__global__ __launch_bounds__(256) void k_gemmVA(const float* __restrict__ Wvla, const float* __restrict__ Wvlp,
                                                const float* __restrict__ Wvld,
                                                const float* __restrict__ Wga, const float* __restrict__ Wgp,
                                                const float* __restrict__ Wgd,
                                                int layer, float* __restrict__ ws) {
    __shared__ float xs[16][H];
    __shared__ float vs[16][H];
    int g = blockIdx.x / 202, tb = blockIdx.x % 202;
    int rowbase = tb * 16;
    const float* x0 = ws + OFF_X0;
    const float* XO = ws + OFF_XO + g*RV*H;
    for (int e = 0; e < 8; e++) {
        int lin = threadIdx.x + e*256;
        int r = lin >> 7, k = lin & 127;
        int b, node; decode_vrow(rowbase + r, b, node);
        xs[r][k] = (layer == 0) ? x0[(b*NA + node)*H + k] : combined(XO, b, node, k);
    }
    __syncthreads();
    int seg = rowbase < R1 ? 0 : (rowbase < R1 + R2 ? 1 : 2);
    const float* W = (seg == 0 ? Wvla : (seg == 1 ? Wvlp : Wvld)) + layer*H*H;
    int col = threadIdx.x & 127, half = threadIdx.x >> 7;
    float acc[8] = {0,0,0,0,0,0,0,0};
    for (int k = 0; k < H; k++) {
        float w = W[k*H + col];
        #pragma unroll
        for (int rr = 0; rr < 8; rr++) acc[rr] += xs[half + rr*2][k] * w;
    }
    float* V = ws + OFF_V + g*RV*H;
    #pragma unroll
    for (int rr = 0; rr < 8; rr++) {
        vs[half + rr*2][col] = acc[rr];
        V[(rowbase + half + rr*2)*H + col] = acc[rr];
    }
    __syncthreads();
    const float* Wg = (seg == 0 ? Wga : (seg == 1 ? Wgp : Wgd)) + layer*320*H;
    int c = threadIdx.x;
    const float* wb = Wg + ((c >> 7) * H) * H + (c & 127);
    float a2[16];
    #pragma unroll
    for (int rr = 0; rr < 16; rr++) a2[rr] = 0.0f;
    for (int k = 0; k < H; k++) {
        float w = wb[k*H];
        #pragma unroll
        for (int rr = 0; rr < 16; rr++) a2[rr] += vs[rr][k] * w;
    }
    float* AB = ws + OFF_AB + g*RV*2*H;
    #pragma unroll
    for (int rr = 0; rr < 16; rr++) AB[(rowbase + rr)*256 + c] = a2[rr];
}

// ---- fused attention: J j-rows per block, LDS-staged mask/edge, online softmax ----
__global__ __launch_bounds__(128) void k_attn(const float* __restrict__ ea_d, const float* __restrict__ ea_r,
                                              const int* __restrict__ mask_d, const int* __restrict__ mask_r,
                                              int layer, float* __restrict__ ws) {
    int bx = blockIdx.x;             // 2 * (16*26 + 16*13 + 16*13) = 1664
    int g = bx / 832, r = bx % 832;
    int seg, b, jg, n, o, base;
    if (r < 416)      { seg = 0; b = r / 26; jg = r % 26; n = NA; o = 0;      base = 0; }
    else { r -= 416;
      if (r < 208)    { seg = 1; b = r / 13; jg = r % 13; n = N2; o = D;      base = R1; }
      else { r -= 208;  seg = 2; b = r / 13; jg = r % 13; n = N2; o = D + N2; base = R1 + R2; } }
    int j0 = jg * J;
    int jc = min(J, n - j0);
    int h = threadIdx.x;
    const float* pqr = ws + OFF_PQR + ((g*3 + seg)*3 + layer)*384;
    float P = pqr[h], Q = pqr[128 + h], Rr = pqr[256 + h];
    const float2* ea = (const float2*)(g ? ea_r : ea_d);
    const int* mask = g ? mask_r : mask_d;
    const float* V  = ws + OFF_V  + g*RV*H   + base*H;
    const float* AB = ws + OFF_AB + g*RV*2*H + base*2*H;

    __shared__ int    sm[J][128];
    __shared__ float2 se[J][128];
    if (h < n) {
        int ibase = b*NAE + (o + h)*NA + o + j0;
        #pragma unroll
        for (int jj = 0; jj < J; jj++) {
            int valid = (jj < jc) ? mask[ibase + jj] : 0;
            sm[jj][h] = valid;
            se[jj][h] = valid ? ea[ibase + jj] : make_float2(0.f, 0.f);
        }
    }
    __syncthreads();

    float Aj[J], mx[J], lsum[J], acc[J];
    #pragma unroll
    for (int jj = 0; jj < J; jj++) {
        Aj[jj] = (jj < jc) ? AB[(b*n + j0 + jj)*256 + h] : 0.0f;
        mx[jj] = -INFINITY; lsum[jj] = 0.0f; acc[jj] = 0.0f;
    }
    for (int i = 0; i < n; i++) {
        float Bi = AB[(b*n + i)*256 + 128 + h];
        float Vi = V[(b*n + i)*H + h];
        #pragma unroll
        for (int jj = 0; jj < J; jj++) {
            if (sm[jj][i]) {
                float2 ev = se[jj][i];
                float t = Aj[jj] + Bi + ev.x*P + ev.y*Q + Rr;
                t = t >= 0.0f ? t : SLOPE*t;
                float nm = fmaxf(mx[jj], t);
                float sc = __expf(mx[jj] - nm);
                float p  = __expf(t - nm);
                lsum[jj] = lsum[jj]*sc + p;
                acc[jj]  = acc[jj]*sc + p*Vi;
                mx[jj] = nm;
            }
        }
    }
    float* XO = ws + OFF_XO + g*RV*H + base*H;
    for (int jj = 0; jj < jc; jj++)
        XO[(b*n + j0 + jj)*H + h] = acc[jj] / lsum[jj];
}

// ---- fused feed-forward: xf=combined; H1=relu(xf@W1+b1); Z=xf+H1@W2+b2; BN stats ----
__global__ __launch_bounds__(256) void k_ff(const float* __restrict__ ffw1, const float* __restrict__ ffb1,
                                            const float* __restrict__ ffw2, const float* __restrict__ ffb2,
                                            float* __restrict__ ws) {
    __shared__ float xs[16][H];
    __shared__ float hs[16][H];
    int g = blockIdx.x / 102, tb = blockIdx.x % 102;
    int rowbase = tb * 16;
    const float* XO = ws + OFF_XO + g*RV*H;
    for (int e = 0; e < 8; e++) {
        int lin = threadIdx.x + e*256;
        int r = lin >> 7, k = lin & 127;
        int ridx = rowbase + r;
        int b = ridx / NA, node = ridx % NA;
        xs[r][k] = combined(XO, b, node, k);
    }
    __syncthreads();
    int col = threadIdx.x & 127, half = threadIdx.x >> 7;
    float acc[8] = {0,0,0,0,0,0,0,0};
    for (int k = 0; k < H; k++) {
        float w = ffw1[k*H + col];
        #pragma unroll
        for (int rr = 0; rr < 8; rr++) acc[rr] += xs[half + rr*2][k] * w;
    }
    float b1 = ffb1[col];
    #pragma unroll
    for (int rr = 0; rr < 8; rr++) {
        float hv = acc[rr] + b1;
        hs[half + rr*2][col] = hv > 0.0f ? hv : 0.0f;
    }
    __syncthreads();
    #pragma unroll
    for (int rr = 0; rr < 8; rr++) acc[rr] = 0.0f;
    for (int k = 0; k < H; k++) {
        float w = ffw2[k*H + col];
        #pragma unroll
        for (int rr = 0; rr < 8; rr++) acc[rr] += hs[half + rr*2][k] * w;
    }
    float b2 = ffb2[col];
    float* Z = ws + OFF_Z + g*R1*H;
    float ls = 0, lss = 0;
    #pragma unroll
    for (int rr = 0; rr < 8; rr++) {
        int row = rowbase + half + rr*2;
        float z = acc[rr] + b2 + xs[half + rr*2][col];
        Z[row*H + col] = z;
        ls += z; lss += z*z;
    }
    atomicAdd(&ws[ACC_FF + g*256 + col], ls);
    atomicAdd(&ws[ACC_FF + g*256 + 128 + col], lss);
}

// ---- final BN + output ----
__global__ __launch_bounds__(256) void k_f3(const float* __restrict__ bng, const float* __restrict__ bnb,
                                            float* __restrict__ ws, float* __restrict__ out) {
    int eidx = blockIdx.x * 256 + threadIdx.x;   // 2*R1*H total
    int g = eidx / (R1*H);
    int c = eidx & 127;
    float m = ws[ACC_FF + g*256 + c] / 1632.0f;
    float v = ws[ACC_FF + g*256 + 128 + c] / 1632.0f - m*m;
    float sc = bng[c] * rsqrtf(v + EPS);
    float sh = bnb[c] - m*sc;
    out[eidx] = ws[OFF_Z + eidx] * sc + sh;
}

extern "C" void kernel_launch(void* const* d_in, const int* in_sizes, int n_in,
                              void* d_out, int out_size, void* d_ws, size_t ws_size,
                              hipStream_t stream) {
    const float* x    = (const float*)d_in[0];
    const float* dm   = (const float*)d_in[1];
    const float* tw   = (const float*)d_in[2];
    const float* ead  = (const float*)d_in[3];
    const float* ear  = (const float*)d_in[4];
    const float* W0   = (const float*)d_in[5];
    const float* W1   = (const float*)d_in[6];
    const float* W2   = (const float*)d_in[7];
    const float* W3   = (const float*)d_in[8];
    const float* W4   = (const float*)d_in[9];
    const float* b0g  = (const float*)d_in[10];
    const float* b0b  = (const float*)d_in[11];
    const float* b1g  = (const float*)d_in[12];
    const float* b1b  = (const float*)d_in[13];
    const float* b2g  = (const float*)d_in[14];
    const float* b2b  = (const float*)d_in[15];
    const float* b3g  = (const float*)d_in[16];
    const float* b3b  = (const float*)d_in[17];
    const float* b4g  = (const float*)d_in[18];
    const float* b4b  = (const float*)d_in[19];
    const float* ffw1 = (const float*)d_in[20];
    const float* ffb1 = (const float*)d_in[21];
    const float* ffw2 = (const float*)d_in[22];
    const float* ffb2 = (const float*)d_in[23];
    const float* bng  = (const float*)d_in[24];
    const float* bnb  = (const float*)d_in[25];
    const float* Wvla = (const float*)d_in[26];
    const float* Wvlp = (const float*)d_in[27];
    const float* Wvld = (const float*)d_in[28];
    const float* Wga  = (const float*)d_in[29];
    const float* Wgp  = (const float*)d_in[30];
    const float* Wgd  = (const float*)d_in[31];
    const int* mask_d = (const int*)d_in[33];
    const int* mask_r = (const int*)d_in[34];
    float* ws = (float*)d_ws;
    float* out = (float*)d_out;

    k_zero    <<<1, 256, 0, stream>>>(ws);
    k_moments <<<256, 256, 0, stream>>>(ead, ear, ws);
    k_st      <<<1, 128, 0, stream>>>(W3, W4, b3g, b3b, b4g, b4b, ws);
    k_pqr     <<<18, 128, 0, stream>>>(Wga, Wgp, Wgd, ws);
    k_nodeinit<<<102, 128, 0, stream>>>(x, dm, tw, W0, W1, W2, ws);
    k_nodenorm<<<102, 128, 0, stream>>>(b0g, b0b, b1g, b1b, b2g, b2b, ws);
    for (int l = 0; l < L; l++) {
        k_gemmVA<<<404, 256, 0, stream>>>(Wvla, Wvlp, Wvld, Wga, Wgp, Wgd, l, ws);
        k_attn  <<<1664, 128, 0, stream>>>(ead, ear, mask_d, mask_r, l, ws);
    }
    k_ff<<<204, 256, 0, stream>>>(ffw1, ffb1, ffw2, ffb2, ws);
    k_f3<<<1632, 256, 0, stream>>>(bng, bnb, ws, out);
}

// Round 5
// 424.147 us; speedup vs baseline: 1.4978x; 1.0654x over previous
//
#include <hip/hip_runtime.h>
#include <stdint.h>

#define B 16
#define D 2
#define NN 100
#define N2 50
#define NA 102
#define H 128
#define HE 64
#define L 3
#define SLOPE 0.2f
#define EPS 1e-5f

#define NAE (NA*NA)          // 10404
#define EN (B*NAE)           // 166464 edge rows per graph
#define R1 (B*NA)            // 1632
#define R2 (B*N2)            // 800
#define RV (R1 + 2*R2)       // 3232 rows in V/AB/XO per graph
#define NC 202               // per-batch row count in the reference's scrambled reshape
#define J 8                  // j-rows per attention block

// ---- workspace layout (float offsets) ----
#define ACC_MOM   0            // 2 graphs * 5 moments
#define ACC_NODE  16           // 3 segs * (128 sum + 128 sumsq)
#define ACC_FF    1024         // 2 graphs * (128 sum + 128 sumsq)
#define OFF_PQR   2560         // 2*3*3 * (3*128)
#define OFF_X0    9472
#define OFF_V     (OFF_X0 + R1*H)
#define OFF_AB    (OFF_V + 2*RV*H)
#define OFF_XO    (OFF_AB + 2*RV*2*H)
#define OFF_Z     (OFF_XO + 2*RV*H)

// decode a V/AB/XO row index -> (batch, node)  [flat concat order: X1 | X2 | X3]
__device__ __forceinline__ void decode_vrow(int ridx, int& b, int& node) {
    if (ridx < R1) { b = ridx / NA; node = ridx % NA; }
    else if (ridx < R1 + R2) { int p = ridx - R1; b = p / N2; node = D + p % N2; }
    else { int p = ridx - R1 - R2; b = p / N2; node = D + N2 + p % N2; }
}
// decode node-init virtual row -> (batch, node); 32 dep / 800 pk / 800 dl
__device__ __forceinline__ void decode_nrow(int vr, int& b, int& node) {
    if (vr < 32) { b = vr >> 1; node = vr & 1; }
    else if (vr < 832) { int p = vr - 32; b = p / N2; node = D + p % N2; }
    else { int p = vr - 832; b = p / N2; node = D + N2 + p % N2; }
}
// conv output per the reference's EXACT (scrambled reshape) semantics:
// Xc[b,q] = flat[b*202+q], flat = [X1(1632); X2(800); X3(800)]
// out[b,n] = Xc[b,n] + (n>=D ? Xc[b,n+100] : 0)
__device__ __forceinline__ float combined(const float* __restrict__ XO, int b, int node, int k) {
    float v = XO[(b*NC + node)*H + k];
    if (node >= D) v += XO[(b*NC + node + 100)*H + k];
    return v;
}

// ---- zero the accumulator region (graph-capture-safe) ----
__global__ __launch_bounds__(256) void k_zero(float* __restrict__ ws) {
    for (int i = threadIdx.x; i < 2048; i += 256) ws[i] = 0.0f;
}

// ---- edge-attr moments: 5 scalar sums per graph ----
__global__ __launch_bounds__(256) void k_moments(const float* __restrict__ ea_d,
                                                 const float* __restrict__ ea_r,
                                                 float* __restrict__ ws) {
    int g = blockIdx.x >> 7;
    int bb = blockIdx.x & 127;
    const float2* ea = (const float2*)(g ? ea_r : ea_d);
    float s0 = 0, s1 = 0, s00 = 0, s11 = 0, s01 = 0;
    for (int idx = bb*256 + threadIdx.x; idx < EN; idx += 128*256) {
        float2 v = ea[idx];
        s0 += v.x; s1 += v.y; s00 += v.x*v.x; s11 += v.y*v.y; s01 += v.x*v.y;
    }
    __shared__ float sd[256];
    float vals[5] = {s0, s1, s00, s11, s01};
    for (int q = 0; q < 5; q++) {
        sd[threadIdx.x] = vals[q];
        __syncthreads();
        for (int off = 128; off > 0; off >>= 1) {
            if (threadIdx.x < off) sd[threadIdx.x] += sd[threadIdx.x + off];
            __syncthreads();
        }
        if (threadIdx.x == 0) atomicAdd(&ws[ACC_MOM + g*5 + q], sd[0]);
        __syncthreads();
    }
}

// ---- fold edge BN (from moments) and we into per-channel P/Q/R ----
__global__ __launch_bounds__(128) void k_stpqr(const float* __restrict__ W3, const float* __restrict__ W4,
                                               const float* __restrict__ b3g, const float* __restrict__ b3b,
                                               const float* __restrict__ b4g, const float* __restrict__ b4b,
                                               const float* __restrict__ Wga, const float* __restrict__ Wgp,
                                               const float* __restrict__ Wgd, float* __restrict__ ws) {
    int bx = blockIdx.x;           // 18 = 2 graphs * 3 segs * 3 layers
    int g = bx / 9, rem = bx % 9, seg = rem / 3, l = rem % 3;
    __shared__ float st[192];
    int t = threadIdx.x;
    if (t < 64) {
        const float* W  = g ? W4 : W3;
        const float* gv = g ? b4g : b3g;
        const float* bv = g ? b4b : b3b;
        float Nr = (float)EN;
        float S0 = ws[ACC_MOM + g*5 + 0], S1 = ws[ACC_MOM + g*5 + 1];
        float S00 = ws[ACC_MOM + g*5 + 2], S11 = ws[ACC_MOM + g*5 + 3], S01 = ws[ACC_MOM + g*5 + 4];
        float w0 = W[t], w1 = W[64 + t];
        float m = (S0*w0 + S1*w1) / Nr;
        float E2 = (S00*w0*w0 + 2.0f*S01*w0*w1 + S11*w1*w1) / Nr;
        float var = E2 - m*m;
        float s = gv[t] * rsqrtf(var + EPS);
        st[t] = w0 * s; st[64 + t] = w1 * s; st[128 + t] = bv[t] - m*s;
    }
    __syncthreads();
    int h = t;
    const float* Wg = (seg == 0 ? Wga : (seg == 1 ? Wgp : Wgd)) + l*320*H;
    float P = 0, Q = 0, Rr = 0;
    for (int cc = 0; cc < HE; cc++) {
        float w = Wg[(2*H + cc)*H + h];
        P += st[cc]*w; Q += st[64 + cc]*w; Rr += st[128 + cc]*w;
    }
    float* o = ws + OFF_PQR + ((g*3 + seg)*3 + l)*384;
    o[h] = P; o[128 + h] = Q; o[256 + h] = Rr;
}

// ---- initial node embeddings: linear + stat accumulation ----
__global__ __launch_bounds__(128) void k_nodeinit(const float* __restrict__ x, const float* __restrict__ dm,
                                                  const float* __restrict__ tw,
                                                  const float* __restrict__ W0, const float* __restrict__ W1,
                                                  const float* __restrict__ W2, float* __restrict__ ws) {
    int c = threadIdx.x, bx = blockIdx.x;
    int seg = (bx < 2) ? 0 : (bx < 52 ? 1 : 2);
    const float* W = seg == 0 ? W0 : (seg == 1 ? W1 : W2);
    int nf = seg == 1 ? 10 : 5;
    float w[10];
    for (int f = 0; f < nf; f++) w[f] = W[f*H + c];
    float* x0 = ws + OFF_X0;
    float ls = 0, lss = 0;
    for (int r = 0; r < 16; r++) {
        int vr = bx*16 + r;
        int b, node; decode_nrow(vr, b, node);
        int row = b*NA + node;
        float y = x[row*2]*w[0] + x[row*2+1]*w[1] + dm[row]*w[2]
                + tw[row*2]*w[3] + tw[row*2+1]*w[4];
        if (seg == 1) {
            int r2 = row + N2;
            y += x[r2*2]*w[5] + x[r2*2+1]*w[6] + dm[r2]*w[7]
               + tw[r2*2]*w[8] + tw[r2*2+1]*w[9];
        }
        x0[row*H + c] = y;
        ls += y; lss += y*y;
    }
    atomicAdd(&ws[ACC_NODE + seg*256 + c], ls);
    atomicAdd(&ws[ACC_NODE + seg*256 + 128 + c], lss);
}

__global__ __launch_bounds__(128) void k_nodenorm(const float* __restrict__ b0g, const float* __restrict__ b0b,
                                                  const float* __restrict__ b1g, const float* __restrict__ b1b,
                                                  const float* __restrict__ b2g, const float* __restrict__ b2b,
                                                  float* __restrict__ ws) {
    int c = threadIdx.x, bx = blockIdx.x;
    int seg = (bx < 2) ? 0 : (bx < 52 ? 1 : 2);
    float cnt = seg == 0 ? 32.0f : 800.0f;
    float m = ws[ACC_NODE + seg*256 + c] / cnt;
    float v = ws[ACC_NODE + seg*256 + 128 + c] / cnt - m*m;
    const float* gp = seg == 0 ? b0g : (seg == 1 ? b1g : b2g);
    const float* bp = seg == 0 ? b0b : (seg == 1 ? b1b : b2b);
    float sc = gp[c] * rsqrtf(v + EPS);
    float sh = bp[c] - m*sc;
    float* x0 = ws + OFF_X0;
    for (int r = 0; r < 16; r++) {
        int vr = bx*16 + r;
        int b, node; decode_nrow(vr, b, node);
        int row = b*NA + node;
        x0[row*H + c] = x0[row*H + c]*sc + sh;
    }
}

// ---- fused GEMM: x->V (Wvl) then V->AB ([wi|wj]) per 16-row tile ----
__global__ __launch_bounds__(256) void k_gemmVA(const float* __restrict__ Wvla, const float* __restrict__ Wvlp,
                                                const float* __restrict__ Wvld,
                                                const float* __restrict__ Wga, const float* __restrict__ Wgp,
                                                const float* __restrict__ Wgd,
                                                int layer, float* __restrict__ ws) {
    __shared__ float xs[16][H];
    __shared__ float vs[16][H];
    int g = blockIdx.x / 202, tb = blockIdx.x % 202;
    int rowbase = tb * 16;
    const float* x0 = ws + OFF_X0;
    const float* XO = ws + OFF_XO + g*RV*H;
    for (int e = 0; e < 8; e++) {
        int lin = threadIdx.x + e*256;
        int r = lin >> 7, k = lin & 127;
        int b, node; decode_vrow(rowbase + r, b, node);
        xs[r][k] = (layer == 0) ? x0[(b*NA + node)*H + k] : combined(XO, b, node, k);
    }
    __syncthreads();
    int seg = rowbase < R1 ? 0 : (rowbase < R1 + R2 ? 1 : 2);
    const float* W = (seg == 0 ? Wvla : (seg == 1 ? Wvlp : Wvld)) + layer*H*H;
    int col = threadIdx.x & 127, half = threadIdx.x >> 7;
    float acc[8] = {0,0,0,0,0,0,0,0};
    for (int k = 0; k < H; k++) {
        float w = W[k*H + col];
        #pragma unroll
        for (int rr = 0; rr < 8; rr++) acc[rr] += xs[half + rr*2][k] * w;
    }
    float* V = ws + OFF_V + g*RV*H;
    #pragma unroll
    for (int rr = 0; rr < 8; rr++) {
        vs[half + rr*2][col] = acc[rr];
        V[(rowbase + half + rr*2)*H + col] = acc[rr];
    }
    __syncthreads();
    const float* Wg = (seg == 0 ? Wga : (seg == 1 ? Wgp : Wgd)) + layer*320*H;
    int c = threadIdx.x;
    const float* wb = Wg + ((c >> 7) * H) * H + (c & 127);
    float a2[16];
    #pragma unroll
    for (int rr = 0; rr < 16; rr++) a2[rr] = 0.0f;
    for (int k = 0; k < H; k++) {
        float w = wb[k*H];
        #pragma unroll
        for (int rr = 0; rr < 16; rr++) a2[rr] += vs[rr][k] * w;
    }
    float* AB = ws + OFF_AB + g*RV*2*H;
    #pragma unroll
    for (int rr = 0; rr < 16; rr++) AB[(rowbase + rr)*256 + c] = a2[rr];
}

// ---- fused attention v2: J=8 j-rows, split-i halves, max-free softmax ----
__global__ __launch_bounds__(256) void k_attn(const float* __restrict__ ea_d, const float* __restrict__ ea_r,
                                              const int* __restrict__ mask_d, const int* __restrict__ mask_r,
                                              int layer, float* __restrict__ ws) {
    // grid: 2 graphs * (16*13 + 16*7 + 16*7) = 864 blocks
    int bx = blockIdx.x;
    int g = bx / 432, r = bx % 432;
    int seg, b, jg, n, o, base;
    if (r < 208)      { seg = 0; b = r / 13; jg = r % 13; n = NA; o = 0;      base = 0; }
    else { r -= 208;
      if (r < 112)    { seg = 1; b = r / 7;  jg = r % 7;  n = N2; o = D;      base = R1; }
      else { r -= 112;  seg = 2; b = r / 7;  jg = r % 7;  n = N2; o = D + N2; base = R1 + R2; } }
    int j0 = jg * J;
    int jc = min(J, n - j0);
    int tid = threadIdx.x;
    int h = tid & 127, halfid = tid >> 7;
    const float* pqr = ws + OFF_PQR + ((g*3 + seg)*3 + layer)*384;
    float P = pqr[h], Q = pqr[128 + h], Rr = pqr[256 + h];
    const float2* ea = (const float2*)(g ? ea_r : ea_d);
    const int* mask = g ? mask_r : mask_d;
    const float* V  = ws + OFF_V  + g*RV*H   + base*H;
    const float* AB = ws + OFF_AB + g*RV*2*H + base*2*H;

    __shared__ float smem[2560];                 // 10 KiB, aliased regions
    int*    sm = (int*)smem;                     // [J][104] ints  (3328 B)
    float2* se = (float2*)(smem + 832);          // [J][104] f2    (6656 B)

    if (tid < n) {
        int ibase = g ? 0 : 0;  // keep compiler calm
        ibase = b*NAE + (o + tid)*NA + o + j0;
        #pragma unroll
        for (int jj = 0; jj < J; jj++) {
            int valid = (jj < jc) ? mask[ibase + jj] : 0;
            sm[jj*104 + tid] = valid;
            se[jj*104 + tid] = valid ? ea[ibase + jj] : make_float2(0.f, 0.f);
        }
    }
    __syncthreads();

    float Aj[J], lsum[J], acc[J];
    #pragma unroll
    for (int jj = 0; jj < J; jj++) {
        Aj[jj] = (jj < jc) ? AB[(b*n + j0 + jj)*256 + h] : 0.0f;
        lsum[jj] = 0.0f; acc[jj] = 0.0f;
    }
    int nh = (n + 1) >> 1;
    int i0 = halfid ? nh : 0;
    int i1 = halfid ? n : nh;
    for (int i = i0; i < i1; i++) {
        float Bi = AB[(b*n + i)*256 + 128 + h];
        float Vi = V[(b*n + i)*H + h];
        float BiR = Bi + Rr;
        #pragma unroll
        for (int jj = 0; jj < J; jj++) {
            if (sm[jj*104 + i]) {
                float2 ev = se[jj*104 + i];
                float t = fmaf(ev.x, P, fmaf(ev.y, Q, Aj[jj] + BiR));
                t = t >= 0.0f ? t : SLOPE*t;
                t = fminf(t, 80.0f);             // overflow guard (inactive in normal range)
                float p = __expf(t);
                lsum[jj] += p;
                acc[jj] = fmaf(p, Vi, acc[jj]);
            }
        }
    }
    __syncthreads();                             // i-loops done; safe to reuse smem
    float* mg = smem;                            // [2][J][128] floats = 8 KiB
    if (halfid == 1) {
        #pragma unroll
        for (int jj = 0; jj < J; jj++) {
            mg[jj*128 + h]        = lsum[jj];
            mg[1024 + jj*128 + h] = acc[jj];
        }
    }
    __syncthreads();
    if (halfid == 0) {
        float* XO = ws + OFF_XO + g*RV*H + base*H;
        for (int jj = 0; jj < jc; jj++) {
            float lt = lsum[jj] + mg[jj*128 + h];
            float at = acc[jj]  + mg[1024 + jj*128 + h];
            XO[(b*n + j0 + jj)*H + h] = at / lt;
        }
    }
}

// ---- fused feed-forward: xf=combined; H1=relu(xf@W1+b1); Z=xf+H1@W2+b2; BN stats ----
__global__ __launch_bounds__(256) void k_ff(const float* __restrict__ ffw1, const float* __restrict__ ffb1,
                                            const float* __restrict__ ffw2, const float* __restrict__ ffb2,
                                            float* __restrict__ ws) {
    __shared__ float xs[16][H];
    __shared__ float hs[16][H];
    int g = blockIdx.x / 102, tb = blockIdx.x % 102;
    int rowbase = tb * 16;
    const float* XO = ws + OFF_XO + g*RV*H;
    for (int e = 0; e < 8; e++) {
        int lin = threadIdx.x + e*256;
        int r = lin >> 7, k = lin & 127;
        int ridx = rowbase + r;
        int b = ridx / NA, node = ridx % NA;
        xs[r][k] = combined(XO, b, node, k);
    }
    __syncthreads();
    int col = threadIdx.x & 127, half = threadIdx.x >> 7;
    float acc[8] = {0,0,0,0,0,0,0,0};
    for (int k = 0; k < H; k++) {
        float w = ffw1[k*H + col];
        #pragma unroll
        for (int rr = 0; rr < 8; rr++) acc[rr] += xs[half + rr*2][k] * w;
    }
    float b1 = ffb1[col];
    #pragma unroll
    for (int rr = 0; rr < 8; rr++) {
        float hv = acc[rr] + b1;
        hs[half + rr*2][col] = hv > 0.0f ? hv : 0.0f;
    }
    __syncthreads();
    #pragma unroll
    for (int rr = 0; rr < 8; rr++) acc[rr] = 0.0f;
    for (int k = 0; k < H; k++) {
        float w = ffw2[k*H + col];
        #pragma unroll
        for (int rr = 0; rr < 8; rr++) acc[rr] += hs[half + rr*2][k] * w;
    }
    float b2 = ffb2[col];
    float* Z = ws + OFF_Z + g*R1*H;
    float ls = 0, lss = 0;
    #pragma unroll
    for (int rr = 0; rr < 8; rr++) {
        int row = rowbase + half + rr*2;
        float z = acc[rr] + b2 + xs[half + rr*2][col];
        Z[row*H + col] = z;
        ls += z; lss += z*z;
    }
    atomicAdd(&ws[ACC_FF + g*256 + col], ls);
    atomicAdd(&ws[ACC_FF + g*256 + 128 + col], lss);
}

// ---- final BN + output ----
__global__ __launch_bounds__(256) void k_f3(const float* __restrict__ bng, const float* __restrict__ bnb,
                                            float* __restrict__ ws, float* __restrict__ out) {
    int eidx = blockIdx.x * 256 + threadIdx.x;   // 2*R1*H total
    int g = eidx / (R1*H);
    int c = eidx & 127;
    float m = ws[ACC_FF + g*256 + c] / 1632.0f;
    float v = ws[ACC_FF + g*256 + 128 + c] / 1632.0f - m*m;
    float sc = bng[c] * rsqrtf(v + EPS);
    float sh = bnb[c] - m*sc;
    out[eidx] = ws[OFF_Z + eidx] * sc + sh;
}

extern "C" void kernel_launch(void* const* d_in, const int* in_sizes, int n_in,
                              void* d_out, int out_size, void* d_ws, size_t ws_size,
                              hipStream_t stream) {
    const float* x    = (const float*)d_in[0];
    const float* dm   = (const float*)d_in[1];
    const float* tw   = (const float*)d_in[2];
    const float* ead  = (const float*)d_in[3];
    const float* ear  = (const float*)d_in[4];
    const float* W0   = (const float*)d_in[5];
    const float* W1   = (const float*)d_in[6];
    const float* W2   = (const float*)d_in[7];
    const float* W3   = (const float*)d_in[8];
    const float* W4   = (const float*)d_in[9];
    const float* b0g  = (const float*)d_in[10];
    const float* b0b  = (const float*)d_in[11];
    const float* b1g  = (const float*)d_in[12];
    const float* b1b  = (const float*)d_in[13];
    const float* b2g  = (const float*)d_in[14];
    const float* b2b  = (const float*)d_in[15];
    const float* b3g  = (const float*)d_in[16];
    const float* b3b  = (const float*)d_in[17];
    const float* b4g  = (const float*)d_in[18];
    const float* b4b  = (const float*)d_in[19];
    const float* ffw1 = (const float*)d_in[20];
    const float* ffb1 = (const float*)d_in[21];
    const float* ffw2 = (const float*)d_in[22];
    const float* ffb2 = (const float*)d_in[23];
    const float* bng  = (const float*)d_in[24];
    const float* bnb  = (const float*)d_in[25];
    const float* Wvla = (const float*)d_in[26];
    const float* Wvlp = (const float*)d_in[27];
    const float* Wvld = (const float*)d_in[28];
    const float* Wga  = (const float*)d_in[29];
    const float* Wgp  = (const float*)d_in[30];
    const float* Wgd  = (const float*)d_in[31];
    const int* mask_d = (const int*)d_in[33];
    const int* mask_r = (const int*)d_in[34];
    float* ws = (float*)d_ws;
    float* out = (float*)d_out;

    k_zero    <<<1, 256, 0, stream>>>(ws);
    k_moments <<<256, 256, 0, stream>>>(ead, ear, ws);
    k_stpqr   <<<18, 128, 0, stream>>>(W3, W4, b3g, b3b, b4g, b4b, Wga, Wgp, Wgd, ws);
    k_nodeinit<<<102, 128, 0, stream>>>(x, dm, tw, W0, W1, W2, ws);
    k_nodenorm<<<102, 128, 0, stream>>>(b0g, b0b, b1g, b1b, b2g, b2b, ws);
    for (int l = 0; l < L; l++) {
        k_gemmVA<<<404, 256, 0, stream>>>(Wvla, Wvlp, Wvld, Wga, Wgp, Wgd, l, ws);
        k_attn  <<<864, 256, 0, stream>>>(ead, ear, mask_d, mask_r, l, ws);
    }
    k_ff<<<204, 256, 0, stream>>>(ffw1, ffb1, ffw2, ffb2, ws);
    k_f3<<<1632, 256, 0, stream>>>(bng, bnb, ws, out);
}

// Round 7
// 391.841 us; speedup vs baseline: 1.6212x; 1.0824x over previous
//
#include <hip/hip_runtime.h>
#include <stdint.h>

#define B 16
#define D 2
#define NN 100
#define N2 50
#define NA 102
#define H 128
#define HE 64
#define L 3
#define SLOPE 0.2f
#define EPS 1e-5f

#define NAE (NA*NA)          // 10404
#define EN (B*NAE)           // 166464 edge rows per graph
#define R1 (B*NA)            // 1632
#define R2 (B*N2)            // 800
#define RV (R1 + 2*R2)       // 3232 rows in V/AB/XO per graph
#define NC 202               // per-batch row count in the reference's scrambled reshape
#define J 4                  // j-rows per attention block

// ---- workspace layout (float offsets) ----
#define ACC_MOM   0            // 2 graphs * 5 moments
#define ACC_NODE  16           // 3 segs * (128 sum + 128 sumsq)
#define ACC_FF    1024         // 2 graphs * (128 sum + 128 sumsq)
#define OFF_PQR   2560         // 2*3*3 * (3*128)
#define OFF_X0    9472
#define OFF_V     (OFF_X0 + R1*H)
#define OFF_AB    (OFF_V + 2*RV*H)
#define OFF_XO    (OFF_AB + 2*RV*2*H)
#define OFF_Z     (OFF_XO + 2*RV*H)

// decode a V/AB/XO row index -> (batch, node)  [flat concat order: X1 | X2 | X3]
__device__ __forceinline__ void decode_vrow(int ridx, int& b, int& node) {
    if (ridx < R1) { b = ridx / NA; node = ridx % NA; }
    else if (ridx < R1 + R2) { int p = ridx - R1; b = p / N2; node = D + p % N2; }
    else { int p = ridx - R1 - R2; b = p / N2; node = D + N2 + p % N2; }
}
// decode node-init virtual row -> (batch, node); 32 dep / 800 pk / 800 dl
__device__ __forceinline__ void decode_nrow(int vr, int& b, int& node) {
    if (vr < 32) { b = vr >> 1; node = vr & 1; }
    else if (vr < 832) { int p = vr - 32; b = p / N2; node = D + p % N2; }
    else { int p = vr - 832; b = p / N2; node = D + N2 + p % N2; }
}
// conv output per the reference's EXACT (scrambled reshape) semantics:
// Xc[b,q] = flat[b*202+q], flat = [X1(1632); X2(800); X3(800)]
// out[b,n] = Xc[b,n] + (n>=D ? Xc[b,n+100] : 0)
__device__ __forceinline__ float combined(const float* __restrict__ XO, int b, int node, int k) {
    float v = XO[(b*NC + node)*H + k];
    if (node >= D) v += XO[(b*NC + node + 100)*H + k];
    return v;
}

// ---- zero the accumulator region (graph-capture-safe) ----
__global__ __launch_bounds__(256) void k_zero(float* __restrict__ ws) {
    for (int i = threadIdx.x; i < 2048; i += 256) ws[i] = 0.0f;
}

// ---- edge-attr moments: 5 scalar sums per graph ----
__global__ __launch_bounds__(256) void k_moments(const float* __restrict__ ea_d,
                                                 const float* __restrict__ ea_r,
                                                 float* __restrict__ ws) {
    int g = blockIdx.x >> 7;
    int bb = blockIdx.x & 127;
    const float2* ea = (const float2*)(g ? ea_r : ea_d);
    float s0 = 0, s1 = 0, s00 = 0, s11 = 0, s01 = 0;
    for (int idx = bb*256 + threadIdx.x; idx < EN; idx += 128*256) {
        float2 v = ea[idx];
        s0 += v.x; s1 += v.y; s00 += v.x*v.x; s11 += v.y*v.y; s01 += v.x*v.y;
    }
    __shared__ float sd[256];
    float vals[5] = {s0, s1, s00, s11, s01};
    for (int q = 0; q < 5; q++) {
        sd[threadIdx.x] = vals[q];
        __syncthreads();
        for (int off = 128; off > 0; off >>= 1) {
            if (threadIdx.x < off) sd[threadIdx.x] += sd[threadIdx.x + off];
            __syncthreads();
        }
        if (threadIdx.x == 0) atomicAdd(&ws[ACC_MOM + g*5 + q], sd[0]);
        __syncthreads();
    }
}

// ---- fold edge BN (from moments) and we into per-channel P/Q/R ----
__global__ __launch_bounds__(128) void k_stpqr(const float* __restrict__ W3, const float* __restrict__ W4,
                                               const float* __restrict__ b3g, const float* __restrict__ b3b,
                                               const float* __restrict__ b4g, const float* __restrict__ b4b,
                                               const float* __restrict__ Wga, const float* __restrict__ Wgp,
                                               const float* __restrict__ Wgd, float* __restrict__ ws) {
    int bx = blockIdx.x;           // 18 = 2 graphs * 3 segs * 3 layers
    int g = bx / 9, rem = bx % 9, seg = rem / 3, l = rem % 3;
    __shared__ float st[192];
    int t = threadIdx.x;
    if (t < 64) {
        const float* W  = g ? W4 : W3;
        const float* gv = g ? b4g : b3g;
        const float* bv = g ? b4b : b3b;
        float Nr = (float)EN;
        float S0 = ws[ACC_MOM + g*5 + 0], S1 = ws[ACC_MOM + g*5 + 1];
        float S00 = ws[ACC_MOM + g*5 + 2], S11 = ws[ACC_MOM + g*5 + 3], S01 = ws[ACC_MOM + g*5 + 4];
        float w0 = W[t], w1 = W[64 + t];
        float m = (S0*w0 + S1*w1) / Nr;
        float E2 = (S00*w0*w0 + 2.0f*S01*w0*w1 + S11*w1*w1) / Nr;
        float var = E2 - m*m;
        float s = gv[t] * rsqrtf(var + EPS);
        st[t] = w0 * s; st[64 + t] = w1 * s; st[128 + t] = bv[t] - m*s;
    }
    __syncthreads();
    int h = t;
    const float* Wg = (seg == 0 ? Wga : (seg == 1 ? Wgp : Wgd)) + l*320*H;
    float P = 0, Q = 0, Rr = 0;
    for (int cc = 0; cc < HE; cc++) {
        float w = Wg[(2*H + cc)*H + h];
        P += st[cc]*w; Q += st[64 + cc]*w; Rr += st[128 + cc]*w;
    }
    float* o = ws + OFF_PQR + ((g*3 + seg)*3 + l)*384;
    o[h] = P; o[128 + h] = Q; o[256 + h] = Rr;
}

// ---- initial node embeddings: linear + stat accumulation ----
__global__ __launch_bounds__(128) void k_nodeinit(const float* __restrict__ x, const float* __restrict__ dm,
                                                  const float* __restrict__ tw,
                                                  const float* __restrict__ W0, const float* __restrict__ W1,
                                                  const float* __restrict__ W2, float* __restrict__ ws) {
    int c = threadIdx.x, bx = blockIdx.x;
    int seg = (bx < 2) ? 0 : (bx < 52 ? 1 : 2);
    const float* W = seg == 0 ? W0 : (seg == 1 ? W1 : W2);
    int nf = seg == 1 ? 10 : 5;
    float w[10];
    for (int f = 0; f < nf; f++) w[f] = W[f*H + c];
    float* x0 = ws + OFF_X0;
    float ls = 0, lss = 0;
    for (int r = 0; r < 16; r++) {
        int vr = bx*16 + r;
        int b, node; decode_nrow(vr, b, node);
        int row = b*NA + node;
        float y = x[row*2]*w[0] + x[row*2+1]*w[1] + dm[row]*w[2]
                + tw[row*2]*w[3] + tw[row*2+1]*w[4];
        if (seg == 1) {
            int r2 = row + N2;
            y += x[r2*2]*w[5] + x[r2*2+1]*w[6] + dm[r2]*w[7]
               + tw[r2*2]*w[8] + tw[r2*2+1]*w[9];
        }
        x0[row*H + c] = y;
        ls += y; lss += y*y;
    }
    atomicAdd(&ws[ACC_NODE + seg*256 + c], ls);
    atomicAdd(&ws[ACC_NODE + seg*256 + 128 + c], lss);
}

__global__ __launch_bounds__(128) void k_nodenorm(const float* __restrict__ b0g, const float* __restrict__ b0b,
                                                  const float* __restrict__ b1g, const float* __restrict__ b1b,
                                                  const float* __restrict__ b2g, const float* __restrict__ b2b,
                                                  float* __restrict__ ws) {
    int c = threadIdx.x, bx = blockIdx.x;
    int seg = (bx < 2) ? 0 : (bx < 52 ? 1 : 2);
    float cnt = seg == 0 ? 32.0f : 800.0f;
    float m = ws[ACC_NODE + seg*256 + c] / cnt;
    float v = ws[ACC_NODE + seg*256 + 128 + c] / cnt - m*m;
    const float* gp = seg == 0 ? b0g : (seg == 1 ? b1g : b2g);
    const float* bp = seg == 0 ? b0b : (seg == 1 ? b1b : b2b);
    float sc = gp[c] * rsqrtf(v + EPS);
    float sh = bp[c] - m*sc;
    float* x0 = ws + OFF_X0;
    for (int r = 0; r < 16; r++) {
        int vr = bx*16 + r;
        int b, node; decode_nrow(vr, b, node);
        int row = b*NA + node;
        x0[row*H + c] = x0[row*H + c]*sc + sh;
    }
}

// ---- fused GEMM: x->V (Wvl) then V->AB ([wi|wj]) per 16-row tile ----
__global__ __launch_bounds__(256) void k_gemmVA(const float* __restrict__ Wvla, const float* __restrict__ Wvlp,
                                                const float* __restrict__ Wvld,
                                                const float* __restrict__ Wga, const float* __restrict__ Wgp,
                                                const float* __restrict__ Wgd,
                                                int layer, float* __restrict__ ws) {
    __shared__ float xs[16][H];
    __shared__ float vs[16][H];
    int g = blockIdx.x / 202, tb = blockIdx.x % 202;
    int rowbase = tb * 16;
    const float* x0 = ws + OFF_X0;
    const float* XO = ws + OFF_XO + g*RV*H;
    for (int e = 0; e < 8; e++) {
        int lin = threadIdx.x + e*256;
        int r = lin >> 7, k = lin & 127;
        int b, node; decode_vrow(rowbase + r, b, node);
        xs[r][k] = (layer == 0) ? x0[(b*NA + node)*H + k] : combined(XO, b, node, k);
    }
    __syncthreads();
    int seg = rowbase < R1 ? 0 : (rowbase < R1 + R2 ? 1 : 2);
    const float* W = (seg == 0 ? Wvla : (seg == 1 ? Wvlp : Wvld)) + layer*H*H;
    int col = threadIdx.x & 127, half = threadIdx.x >> 7;
    float acc[8] = {0,0,0,0,0,0,0,0};
    #pragma unroll 4
    for (int k = 0; k < H; k++) {
        float w = W[k*H + col];
        #pragma unroll
        for (int rr = 0; rr < 8; rr++) acc[rr] += xs[half + rr*2][k] * w;
    }
    float* V = ws + OFF_V + g*RV*H;
    #pragma unroll
    for (int rr = 0; rr < 8; rr++) {
        vs[half + rr*2][col] = acc[rr];
        V[(rowbase + half + rr*2)*H + col] = acc[rr];
    }
    __syncthreads();
    const float* Wg = (seg == 0 ? Wga : (seg == 1 ? Wgp : Wgd)) + layer*320*H;
    int c = threadIdx.x;
    const float* wb = Wg + ((c >> 7) * H) * H + (c & 127);
    float a2[16];
    #pragma unroll
    for (int rr = 0; rr < 16; rr++) a2[rr] = 0.0f;
    #pragma unroll 4
    for (int k = 0; k < H; k++) {
        float w = wb[k*H];
        #pragma unroll
        for (int rr = 0; rr < 16; rr++) a2[rr] += vs[rr][k] * w;
    }
    float* AB = ws + OFF_AB + g*RV*2*H;
    #pragma unroll
    for (int rr = 0; rr < 16; rr++) AB[(rowbase + rr)*256 + c] = a2[rr];
}

// ---- fused attention v3: J=4 j-rows, i split 4-ways (1 quarter/wave), float2 channels ----
__global__ __launch_bounds__(256) void k_attn(const float* __restrict__ ea_d, const float* __restrict__ ea_r,
                                              const int* __restrict__ mask_d, const int* __restrict__ mask_r,
                                              int layer, float* __restrict__ ws) {
    // grid: 2 graphs * (16*26 + 16*13 + 16*13) = 1664 blocks
    int bx = blockIdx.x;
    int g = bx / 832, r = bx % 832;
    int seg, b, jg, n, o, base;
    if (r < 416)      { seg = 0; b = r / 26; jg = r % 26; n = NA; o = 0;      base = 0; }
    else { r -= 416;
      if (r < 208)    { seg = 1; b = r / 13; jg = r % 13; n = N2; o = D;      base = R1; }
      else { r -= 208;  seg = 2; b = r / 13; jg = r % 13; n = N2; o = D + N2; base = R1 + R2; } }
    int j0 = jg * J;
    int jc = min(J, n - j0);
    int tid = threadIdx.x;
    int c = tid & 63, quad = tid >> 6;          // lane pair-channel, i-quarter (== wave id)
    const float* pqr = ws + OFF_PQR + ((g*3 + seg)*3 + layer)*384;
    float2 Pv = ((const float2*)pqr)[c];
    float2 Qv = ((const float2*)(pqr + 128))[c];
    float2 Rv = ((const float2*)(pqr + 256))[c];
    const float2* ea = (const float2*)(g ? ea_r : ea_d);
    const int* mask = g ? mask_r : mask_d;
    const float* V  = ws + OFF_V  + g*RV*H   + base*H;
    const float* AB = ws + OFF_AB + g*RV*2*H + base*2*H;

    __shared__ float smem[3072];                 // 12 KiB, aliased: stage region then merge region
    int*    sm = (int*)smem;                     // [J][104] ints
    float2* se = (float2*)(smem + 448);          // [J][104] float2 (ends at 448+832=1280 < 3072)

    if (tid < n) {
        int ibase = b*NAE + (o + tid)*NA + o + j0;
        #pragma unroll
        for (int jj = 0; jj < J; jj++) {
            int valid = (jj < jc) ? mask[ibase + jj] : 0;
            sm[jj*104 + tid] = valid;
            se[jj*104 + tid] = valid ? ea[ibase + jj] : make_float2(0.f, 0.f);
        }
    }
    __syncthreads();

    float2 Aj[J], lsum[J], acc[J];
    #pragma unroll
    for (int jj = 0; jj < J; jj++) {
        Aj[jj] = (jj < jc) ? ((const float2*)&AB[(b*n + j0 + jj)*256])[c] : make_float2(0.f, 0.f);
        lsum[jj] = make_float2(0.f, 0.f); acc[jj] = make_float2(0.f, 0.f);
    }
    int qs = (n + 3) >> 2;
    int i0 = quad * qs;
    int i1 = min(n, i0 + qs);
    for (int i = i0; i < i1; i++) {
        float2 Bi = *(const float2*)&AB[(b*n + i)*256 + 128 + 2*c];
        float2 Vi = *(const float2*)&V[(b*n + i)*H + 2*c];
        #pragma unroll
        for (int jj = 0; jj < J; jj++) {
            if (sm[jj*104 + i]) {
                float2 ev = se[jj*104 + i];
                float tx = fmaf(ev.x, Pv.x, fmaf(ev.y, Qv.x, Aj[jj].x + Bi.x + Rv.x));
                float ty = fmaf(ev.x, Pv.y, fmaf(ev.y, Qv.y, Aj[jj].y + Bi.y + Rv.y));
                tx = tx >= 0.0f ? tx : SLOPE*tx;
                ty = ty >= 0.0f ? ty : SLOPE*ty;
                tx = fminf(tx, 80.0f); ty = fminf(ty, 80.0f);
                float px = __expf(tx), py = __expf(ty);
                lsum[jj].x += px;              lsum[jj].y += py;
                acc[jj].x = fmaf(px, Vi.x, acc[jj].x);
                acc[jj].y = fmaf(py, Vi.y, acc[jj].y);
            }
        }
    }
    __syncthreads();                             // staging reads done; reuse smem for merge
    // merge layout: [quad-1][jj][64 lanes] in 4 planes of 256 floats per quarter (conflict-free)
    if (quad != 0) {
        float* mg = smem + (quad - 1)*1024;
        #pragma unroll
        for (int jj = 0; jj < J; jj++) {
            mg[jj*64 + c]       = lsum[jj].x;
            mg[256 + jj*64 + c] = lsum[jj].y;
            mg[512 + jj*64 + c] = acc[jj].x;
            mg[768 + jj*64 + c] = acc[jj].y;
        }
    }
    __syncthreads();
    if (quad == 0) {
        float* XO = ws + OFF_XO + g*RV*H + base*H;
        for (int jj = 0; jj < jc; jj++) {
            float lx = lsum[jj].x, ly = lsum[jj].y, ax = acc[jj].x, ay = acc[jj].y;
            #pragma unroll
            for (int q = 0; q < 3; q++) {
                const float* mg = smem + q*1024;
                lx += mg[jj*64 + c];       ly += mg[256 + jj*64 + c];
                ax += mg[512 + jj*64 + c]; ay += mg[768 + jj*64 + c];
            }
            ((float2*)&XO[(b*n + j0 + jj)*H])[c] = make_float2(ax/lx, ay/ly);
        }
    }
}

// ---- fused feed-forward: xf=combined; H1=relu(xf@W1+b1); Z=xf+H1@W2+b2; BN stats ----
__global__ __launch_bounds__(256) void k_ff(const float* __restrict__ ffw1, const float* __restrict__ ffb1,
                                            const float* __restrict__ ffw2, const float* __restrict__ ffb2,
                                            float* __restrict__ ws) {
    __shared__ float xs[16][H];
    __shared__ float hs[16][H];
    int g = blockIdx.x / 102, tb = blockIdx.x % 102;
    int rowbase = tb * 16;
    const float* XO = ws + OFF_XO + g*RV*H;
    for (int e = 0; e < 8; e++) {
        int lin = threadIdx.x + e*256;
        int r = lin >> 7, k = lin & 127;
        int ridx = rowbase + r;
        int b = ridx / NA, node = ridx % NA;
        xs[r][k] = combined(XO, b, node, k);
    }
    __syncthreads();
    int col = threadIdx.x & 127, half = threadIdx.x >> 7;
    float acc[8] = {0,0,0,0,0,0,0,0};
    #pragma unroll 4
    for (int k = 0; k < H; k++) {
        float w = ffw1[k*H + col];
        #pragma unroll
        for (int rr = 0; rr < 8; rr++) acc[rr] += xs[half + rr*2][k] * w;
    }
    float b1 = ffb1[col];
    #pragma unroll
    for (int rr = 0; rr < 8; rr++) {
        float hv = acc[rr] + b1;
        hs[half + rr*2][col] = hv > 0.0f ? hv : 0.0f;
    }
    __syncthreads();
    #pragma unroll
    for (int rr = 0; rr < 8; rr++) acc[rr] = 0.0f;
    #pragma unroll 4
    for (int k = 0; k < H; k++) {
        float w = ffw2[k*H + col];
        #pragma unroll
        for (int rr = 0; rr < 8; rr++) acc[rr] += hs[half + rr*2][k] * w;
    }
    float b2 = ffb2[col];
    float* Z = ws + OFF_Z + g*R1*H;
    float ls = 0, lss = 0;
    #pragma unroll
    for (int rr = 0; rr < 8; rr++) {
        int row = rowbase + half + rr*2;
        float z = acc[rr] + b2 + xs[half + rr*2][col];
        Z[row*H + col] = z;
        ls += z; lss += z*z;
    }
    atomicAdd(&ws[ACC_FF + g*256 + col], ls);
    atomicAdd(&ws[ACC_FF + g*256 + 128 + col], lss);
}

// ---- final BN + output ----
__global__ __launch_bounds__(256) void k_f3(const float* __restrict__ bng, const float* __restrict__ bnb,
                                            float* __restrict__ ws, float* __restrict__ out) {
    int eidx = blockIdx.x * 256 + threadIdx.x;   // 2*R1*H total
    int g = eidx / (R1*H);
    int c = eidx & 127;
    float m = ws[ACC_FF + g*256 + c] / 1632.0f;
    float v = ws[ACC_FF + g*256 + 128 + c] / 1632.0f - m*m;
    float sc = bng[c] * rsqrtf(v + EPS);
    float sh = bnb[c] - m*sc;
    out[eidx] = ws[OFF_Z + eidx] * sc + sh;
}

extern "C" void kernel_launch(void* const* d_in, const int* in_sizes, int n_in,
                              void* d_out, int out_size, void* d_ws, size_t ws_size,
                              hipStream_t stream) {
    const float* x    = (const float*)d_in[0];
    const float* dm   = (const float*)d_in[1];
    const float* tw   = (const float*)d_in[2];
    const float* ead  = (const float*)d_in[3];
    const float* ear  = (const float*)d_in[4];
    const float* W0   = (const float*)d_in[5];
    const float* W1   = (const float*)d_in[6];
    const float* W2   = (const float*)d_in[7];
    const float* W3   = (const float*)d_in[8];
    const float* W4   = (const float*)d_in[9];
    const float* b0g  = (const float*)d_in[10];
    const float* b0b  = (const float*)d_in[11];
    const float* b1g  = (const float*)d_in[12];
    const float* b1b  = (const float*)d_in[13];
    const float* b2g  = (const float*)d_in[14];
    const float* b2b  = (const float*)d_in[15];
    const float* b3g  = (const float*)d_in[16];
    const float* b3b  = (const float*)d_in[17];
    const float* b4g  = (const float*)d_in[18];
    const float* b4b  = (const float*)d_in[19];
    const float* ffw1 = (const float*)d_in[20];
    const float* ffb1 = (const float*)d_in[21];
    const float* ffw2 = (const float*)d_in[22];
    const float* ffb2 = (const float*)d_in[23];
    const float* bng  = (const float*)d_in[24];
    const float* bnb  = (const float*)d_in[25];
    const float* Wvla = (const float*)d_in[26];
    const float* Wvlp = (const float*)d_in[27];
    const float* Wvld = (const float*)d_in[28];
    const float* Wga  = (const float*)d_in[29];
    const float* Wgp  = (const float*)d_in[30];
    const float* Wgd  = (const float*)d_in[31];
    const int* mask_d = (const int*)d_in[33];
    const int* mask_r = (const int*)d_in[34];
    float* ws = (float*)d_ws;
    float* out = (float*)d_out;

    k_zero    <<<1, 256, 0, stream>>>(ws);
    k_moments <<<256, 256, 0, stream>>>(ead, ear, ws);
    k_stpqr   <<<18, 128, 0, stream>>>(W3, W4, b3g, b3b, b4g, b4b, Wga, Wgp, Wgd, ws);
    k_nodeinit<<<102, 128, 0, stream>>>(x, dm, tw, W0, W1, W2, ws);
    k_nodenorm<<<102, 128, 0, stream>>>(b0g, b0b, b1g, b1b, b2g, b2b, ws);
    for (int l = 0; l < L; l++) {
        k_gemmVA<<<404, 256, 0, stream>>>(Wvla, Wvlp, Wvld, Wga, Wgp, Wgd, l, ws);
        k_attn  <<<1664, 256, 0, stream>>>(ead, ear, mask_d, mask_r, l, ws);
    }
    k_ff<<<204, 256, 0, stream>>>(ffw1, ffb1, ffw2, ffb2, ws);
    k_f3<<<1632, 256, 0, stream>>>(bng, bnb, ws, out);
}

// Round 8
// 367.684 us; speedup vs baseline: 1.7278x; 1.0657x over previous
//
#include <hip/hip_runtime.h>
#include <stdint.h>

#define B 16
#define D 2
#define NN 100
#define N2 50
#define NA 102
#define H 128
#define HE 64
#define L 3
#define SLOPE 0.2f
#define EPS 1e-5f

#define NAE (NA*NA)          // 10404
#define EN (B*NAE)           // 166464 edge rows per graph
#define R1 (B*NA)            // 1632
#define R2 (B*N2)            // 800
#define RV (R1 + 2*R2)       // 3232 rows in V/AB/XO per graph
#define NC 202               // per-batch row count in the reference's scrambled reshape
#define J 8                  // j-rows per attention block
#define TI 34                // i-tile rows staged in LDS

// ---- workspace layout (float offsets) ----
#define ACC_MOM   0
#define ACC_NODE  16
#define ACC_FF    1024
#define OFF_PQR   2560
#define OFF_X0    9472
#define OFF_V     (OFF_X0 + R1*H)
#define OFF_AB    (OFF_V + 2*RV*H)
#define OFF_XO    (OFF_AB + 2*RV*2*H)
#define OFF_Z     (OFF_XO + 2*RV*H)

// decode a V/AB/XO row index -> (batch, node)  [flat concat order: X1 | X2 | X3]
__device__ __forceinline__ void decode_vrow(int ridx, int& b, int& node) {
    if (ridx < R1) { b = ridx / NA; node = ridx % NA; }
    else if (ridx < R1 + R2) { int p = ridx - R1; b = p / N2; node = D + p % N2; }
    else { int p = ridx - R1 - R2; b = p / N2; node = D + N2 + p % N2; }
}
// decode node-init virtual row -> (batch, node); 32 dep / 800 pk / 800 dl
__device__ __forceinline__ void decode_nrow(int vr, int& b, int& node) {
    if (vr < 32) { b = vr >> 1; node = vr & 1; }
    else if (vr < 832) { int p = vr - 32; b = p / N2; node = D + p % N2; }
    else { int p = vr - 832; b = p / N2; node = D + N2 + p % N2; }
}
// conv output per the reference's EXACT (scrambled reshape) semantics:
// Xc[b,q] = flat[b*202+q], flat = [X1(1632); X2(800); X3(800)]
// out[b,n] = Xc[b,n] + (n>=D ? Xc[b,n+100] : 0)
__device__ __forceinline__ float combined(const float* __restrict__ XO, int b, int node, int k) {
    float v = XO[(b*NC + node)*H + k];
    if (node >= D) v += XO[(b*NC + node + 100)*H + k];
    return v;
}

__global__ __launch_bounds__(256) void k_zero(float* __restrict__ ws) {
    for (int i = threadIdx.x; i < 2048; i += 256) ws[i] = 0.0f;
}

// ---- edge-attr moments: 5 scalar sums per graph ----
__global__ __launch_bounds__(256) void k_moments(const float* __restrict__ ea_d,
                                                 const float* __restrict__ ea_r,
                                                 float* __restrict__ ws) {
    int g = blockIdx.x >> 7;
    int bb = blockIdx.x & 127;
    const float2* ea = (const float2*)(g ? ea_r : ea_d);
    float s0 = 0, s1 = 0, s00 = 0, s11 = 0, s01 = 0;
    for (int idx = bb*256 + threadIdx.x; idx < EN; idx += 128*256) {
        float2 v = ea[idx];
        s0 += v.x; s1 += v.y; s00 += v.x*v.x; s11 += v.y*v.y; s01 += v.x*v.y;
    }
    __shared__ float sd[256];
    float vals[5] = {s0, s1, s00, s11, s01};
    for (int q = 0; q < 5; q++) {
        sd[threadIdx.x] = vals[q];
        __syncthreads();
        for (int off = 128; off > 0; off >>= 1) {
            if (threadIdx.x < off) sd[threadIdx.x] += sd[threadIdx.x + off];
            __syncthreads();
        }
        if (threadIdx.x == 0) atomicAdd(&ws[ACC_MOM + g*5 + q], sd[0]);
        __syncthreads();
    }
}

// ---- fold edge BN (from moments) and we into per-channel P/Q/R ----
__global__ __launch_bounds__(128) void k_stpqr(const float* __restrict__ W3, const float* __restrict__ W4,
                                               const float* __restrict__ b3g, const float* __restrict__ b3b,
                                               const float* __restrict__ b4g, const float* __restrict__ b4b,
                                               const float* __restrict__ Wga, const float* __restrict__ Wgp,
                                               const float* __restrict__ Wgd, float* __restrict__ ws) {
    int bx = blockIdx.x;           // 18 = 2 graphs * 3 segs * 3 layers
    int g = bx / 9, rem = bx % 9, seg = rem / 3, l = rem % 3;
    __shared__ float st[192];
    int t = threadIdx.x;
    if (t < 64) {
        const float* W  = g ? W4 : W3;
        const float* gv = g ? b4g : b3g;
        const float* bv = g ? b4b : b3b;
        float Nr = (float)EN;
        float S0 = ws[ACC_MOM + g*5 + 0], S1 = ws[ACC_MOM + g*5 + 1];
        float S00 = ws[ACC_MOM + g*5 + 2], S11 = ws[ACC_MOM + g*5 + 3], S01 = ws[ACC_MOM + g*5 + 4];
        float w0 = W[t], w1 = W[64 + t];
        float m = (S0*w0 + S1*w1) / Nr;
        float E2 = (S00*w0*w0 + 2.0f*S01*w0*w1 + S11*w1*w1) / Nr;
        float var = E2 - m*m;
        float s = gv[t] * rsqrtf(var + EPS);
        st[t] = w0 * s; st[64 + t] = w1 * s; st[128 + t] = bv[t] - m*s;
    }
    __syncthreads();
    int h = t;
    const float* Wg = (seg == 0 ? Wga : (seg == 1 ? Wgp : Wgd)) + l*320*H;
    float P = 0, Q = 0, Rr = 0;
    for (int cc = 0; cc < HE; cc++) {
        float w = Wg[(2*H + cc)*H + h];
        P += st[cc]*w; Q += st[64 + cc]*w; Rr += st[128 + cc]*w;
    }
    float* o = ws + OFF_PQR + ((g*3 + seg)*3 + l)*384;
    o[h] = P; o[128 + h] = Q; o[256 + h] = Rr;
}

// ---- initial node embeddings ----
__global__ __launch_bounds__(128) void k_nodeinit(const float* __restrict__ x, const float* __restrict__ dm,
                                                  const float* __restrict__ tw,
                                                  const float* __restrict__ W0, const float* __restrict__ W1,
                                                  const float* __restrict__ W2, float* __restrict__ ws) {
    int c = threadIdx.x, bx = blockIdx.x;
    int seg = (bx < 2) ? 0 : (bx < 52 ? 1 : 2);
    const float* W = seg == 0 ? W0 : (seg == 1 ? W1 : W2);
    int nf = seg == 1 ? 10 : 5;
    float w[10];
    for (int f = 0; f < nf; f++) w[f] = W[f*H + c];
    float* x0 = ws + OFF_X0;
    float ls = 0, lss = 0;
    for (int r = 0; r < 16; r++) {
        int vr = bx*16 + r;
        int b, node; decode_nrow(vr, b, node);
        int row = b*NA + node;
        float y = x[row*2]*w[0] + x[row*2+1]*w[1] + dm[row]*w[2]
                + tw[row*2]*w[3] + tw[row*2+1]*w[4];
        if (seg == 1) {
            int r2 = row + N2;
            y += x[r2*2]*w[5] + x[r2*2+1]*w[6] + dm[r2]*w[7]
               + tw[r2*2]*w[8] + tw[r2*2+1]*w[9];
        }
        x0[row*H + c] = y;
        ls += y; lss += y*y;
    }
    atomicAdd(&ws[ACC_NODE + seg*256 + c], ls);
    atomicAdd(&ws[ACC_NODE + seg*256 + 128 + c], lss);
}

__global__ __launch_bounds__(128) void k_nodenorm(const float* __restrict__ b0g, const float* __restrict__ b0b,
                                                  const float* __restrict__ b1g, const float* __restrict__ b1b,
                                                  const float* __restrict__ b2g, const float* __restrict__ b2b,
                                                  float* __restrict__ ws) {
    int c = threadIdx.x, bx = blockIdx.x;
    int seg = (bx < 2) ? 0 : (bx < 52 ? 1 : 2);
    float cnt = seg == 0 ? 32.0f : 800.0f;
    float m = ws[ACC_NODE + seg*256 + c] / cnt;
    float v = ws[ACC_NODE + seg*256 + 128 + c] / cnt - m*m;
    const float* gp = seg == 0 ? b0g : (seg == 1 ? b1g : b2g);
    const float* bp = seg == 0 ? b0b : (seg == 1 ? b1b : b2b);
    float sc = gp[c] * rsqrtf(v + EPS);
    float sh = bp[c] - m*sc;
    float* x0 = ws + OFF_X0;
    for (int r = 0; r < 16; r++) {
        int vr = bx*16 + r;
        int b, node; decode_nrow(vr, b, node);
        int row = b*NA + node;
        x0[row*H + c] = x0[row*H + c]*sc + sh;
    }
}

// ---- fused GEMM: x->V (Wvl) then V->AB ([wi|wj]); float4 LDS broadcasts ----
__global__ __launch_bounds__(256) void k_gemmVA(const float* __restrict__ Wvla, const float* __restrict__ Wvlp,
                                                const float* __restrict__ Wvld,
                                                const float* __restrict__ Wga, const float* __restrict__ Wgp,
                                                const float* __restrict__ Wgd,
                                                int layer, float* __restrict__ ws) {
    __shared__ float xs[16][H];
    __shared__ float vs[16][H];
    int g = blockIdx.x / 202, tb = blockIdx.x % 202;
    int rowbase = tb * 16;
    const float* x0 = ws + OFF_X0;
    const float* XO = ws + OFF_XO + g*RV*H;
    for (int e = 0; e < 8; e++) {
        int lin = threadIdx.x + e*256;
        int r = lin >> 7, k = lin & 127;
        int b, node; decode_vrow(rowbase + r, b, node);
        xs[r][k] = (layer == 0) ? x0[(b*NA + node)*H + k] : combined(XO, b, node, k);
    }
    __syncthreads();
    int seg = rowbase < R1 ? 0 : (rowbase < R1 + R2 ? 1 : 2);
    const float* W = (seg == 0 ? Wvla : (seg == 1 ? Wvlp : Wvld)) + layer*H*H;
    int col = threadIdx.x & 127, half = threadIdx.x >> 7;
    float acc[8] = {0,0,0,0,0,0,0,0};
    const float* Wp = W + col;
    for (int k4 = 0; k4 < 32; k4++) {
        float w0 = Wp[(4*k4+0)*H], w1 = Wp[(4*k4+1)*H], w2 = Wp[(4*k4+2)*H], w3 = Wp[(4*k4+3)*H];
        #pragma unroll
        for (int rr = 0; rr < 8; rr++) {
            float4 x4 = *(const float4*)&xs[half + rr*2][4*k4];
            acc[rr] = fmaf(x4.w, w3, fmaf(x4.z, w2, fmaf(x4.y, w1, fmaf(x4.x, w0, acc[rr]))));
        }
    }
    float* V = ws + OFF_V + g*RV*H;
    #pragma unroll
    for (int rr = 0; rr < 8; rr++) {
        vs[half + rr*2][col] = acc[rr];
        V[(rowbase + half + rr*2)*H + col] = acc[rr];
    }
    __syncthreads();
    const float* Wg = (seg == 0 ? Wga : (seg == 1 ? Wgp : Wgd)) + layer*320*H;
    int c = threadIdx.x;
    const float* wb = Wg + ((c >> 7) * H) * H + (c & 127);
    float a2[16];
    #pragma unroll
    for (int rr = 0; rr < 16; rr++) a2[rr] = 0.0f;
    for (int k4 = 0; k4 < 32; k4++) {
        float w0 = wb[(4*k4+0)*H], w1 = wb[(4*k4+1)*H], w2 = wb[(4*k4+2)*H], w3 = wb[(4*k4+3)*H];
        #pragma unroll
        for (int rr = 0; rr < 16; rr++) {
            float4 v4 = *(const float4*)&vs[rr][4*k4];
            a2[rr] = fmaf(v4.w, w3, fmaf(v4.z, w2, fmaf(v4.y, w1, fmaf(v4.x, w0, a2[rr]))));
        }
    }
    float* AB = ws + OFF_AB + g*RV*2*H;
    #pragma unroll
    for (int rr = 0; rr < 16; rr++) AB[(rowbase + rr)*256 + c] = a2[rr];
}

// ---- fused attention v4: LDS-tiled B/V, j-per-wave, bitmask, XCD swizzle ----
// grid: (8, 108). xcd = blockIdx.x; y -> 4 combos/xcd * 27 blocks/combo.
__global__ __launch_bounds__(256) void k_attn(const float* __restrict__ ea_d, const float* __restrict__ ea_r,
                                              const int* __restrict__ mask_d, const int* __restrict__ mask_r,
                                              int layer, float* __restrict__ ws) {
    int k = blockIdx.x, y = blockIdx.y;
    int ci = y / 27, r = y % 27;
    int combo = k + 8*ci;            // 0..31
    int g = combo >> 4, b = combo & 15;
    int seg, jg, n, o, base;
    if (r < 13)      { seg = 0; jg = r;      n = NA; o = 0;      base = 0; }
    else if (r < 20) { seg = 1; jg = r - 13; n = N2; o = D;      base = R1; }
    else             { seg = 2; jg = r - 20; n = N2; o = D + N2; base = R1 + R2; }
    int j0 = jg * J;
    int jc = min(J, n - j0);
    int tid = threadIdx.x;
    int c = tid & 63, quad = tid >> 6;
    int jj0 = 2*quad, jj1 = 2*quad + 1;

    const float* pqr = ws + OFF_PQR + ((g*3 + seg)*3 + layer)*384;
    float2 Pv = ((const float2*)pqr)[c];
    float2 Qv = ((const float2*)(pqr + 128))[c];
    float2 Rv = ((const float2*)(pqr + 256))[c];
    const float2* ea = (const float2*)(g ? ea_r : ea_d);
    const int* mask = g ? mask_r : mask_d;
    const float* V  = ws + OFF_V  + g*RV*H   + base*H;
    const float* AB = ws + OFF_AB + g*RV*2*H + base*2*H;

    __shared__ float2 Bs[TI][64];
    __shared__ float2 Vs[TI][64];
    __shared__ float2 se[J][104];
    __shared__ int    msk_s[104];

    // one-time stage: per-i bitmask over J j's + edge float2s
    if (tid < n) {
        int ibase = b*NAE + (o + tid)*NA + o + j0;
        int bits = 0;
        #pragma unroll
        for (int jj = 0; jj < J; jj++) {
            int valid = (jj < jc) ? (mask[ibase + jj] != 0) : 0;
            bits |= valid << jj;
            se[jj][tid] = valid ? ea[ibase + jj] : make_float2(0.f, 0.f);
        }
        msk_s[tid] = bits;
    }

    // per-wave j state
    float2 Aj0 = make_float2(0.f, 0.f), Aj1 = make_float2(0.f, 0.f);
    if (jj0 < jc) Aj0 = *(const float2*)&AB[(b*n + j0 + jj0)*256 + 2*c];
    if (jj1 < jc) Aj1 = *(const float2*)&AB[(b*n + j0 + jj1)*256 + 2*c];
    float A0x = Aj0.x + Rv.x, A0y = Aj0.y + Rv.y;
    float A1x = Aj1.x + Rv.x, A1y = Aj1.y + Rv.y;
    float2 l0 = make_float2(0.f, 0.f), a0 = make_float2(0.f, 0.f);
    float2 l1 = make_float2(0.f, 0.f), a1 = make_float2(0.f, 0.f);

    for (int t0 = 0; t0 < n; t0 += TI) {
        int rows = min(TI, n - t0);
        __syncthreads();                       // prev tile consumed (and stage visible on 1st iter)
        for (int idx = tid; idx < rows*64; idx += 256) {
            int ir = idx >> 6, cc = idx & 63;
            int gi = b*n + t0 + ir;
            Bs[ir][cc] = *(const float2*)&AB[gi*256 + 128 + 2*cc];
            Vs[ir][cc] = *(const float2*)&V[gi*128 + 2*cc];
        }
        __syncthreads();
        for (int ir = 0; ir < rows; ir++) {
            int i = t0 + ir;
            int bits = msk_s[i];
            if (!(bits & ((1<<jj0) | (1<<jj1)))) continue;
            float2 Bi = Bs[ir][c];
            float2 Vi = Vs[ir][c];
            if (bits & (1<<jj0)) {
                float2 ev = se[jj0][i];
                float tx = fmaf(ev.x, Pv.x, fmaf(ev.y, Qv.x, A0x + Bi.x));
                float ty = fmaf(ev.x, Pv.y, fmaf(ev.y, Qv.y, A0y + Bi.y));
                tx = fminf(fmaxf(tx, SLOPE*tx), 80.0f);
                ty = fminf(fmaxf(ty, SLOPE*ty), 80.0f);
                float px = __expf(tx), py = __expf(ty);
                l0.x += px; l0.y += py;
                a0.x = fmaf(px, Vi.x, a0.x); a0.y = fmaf(py, Vi.y, a0.y);
            }
            if (bits & (1<<jj1)) {
                float2 ev = se[jj1][i];
                float tx = fmaf(ev.x, Pv.x, fmaf(ev.y, Qv.x, A1x + Bi.x));
                float ty = fmaf(ev.x, Pv.y, fmaf(ev.y, Qv.y, A1y + Bi.y));
                tx = fminf(fmaxf(tx, SLOPE*tx), 80.0f);
                ty = fminf(fmaxf(ty, SLOPE*ty), 80.0f);
                float px = __expf(tx), py = __expf(ty);
                l1.x += px; l1.y += py;
                a1.x = fmaf(px, Vi.x, a1.x); a1.y = fmaf(py, Vi.y, a1.y);
            }
        }
    }
    float* XO = ws + OFF_XO + g*RV*H + base*H;
    if (jj0 < jc)
        ((float2*)&XO[(b*n + j0 + jj0)*H])[c] = make_float2(a0.x/l0.x, a0.y/l0.y);
    if (jj1 < jc)
        ((float2*)&XO[(b*n + j0 + jj1)*H])[c] = make_float2(a1.x/l1.x, a1.y/l1.y);
}

// ---- fused feed-forward ----
__global__ __launch_bounds__(256) void k_ff(const float* __restrict__ ffw1, const float* __restrict__ ffb1,
                                            const float* __restrict__ ffw2, const float* __restrict__ ffb2,
                                            float* __restrict__ ws) {
    __shared__ float xs[16][H];
    __shared__ float hs[16][H];
    int g = blockIdx.x / 102, tb = blockIdx.x % 102;
    int rowbase = tb * 16;
    const float* XO = ws + OFF_XO + g*RV*H;
    for (int e = 0; e < 8; e++) {
        int lin = threadIdx.x + e*256;
        int r = lin >> 7, k = lin & 127;
        int ridx = rowbase + r;
        int b = ridx / NA, node = ridx % NA;
        xs[r][k] = combined(XO, b, node, k);
    }
    __syncthreads();
    int col = threadIdx.x & 127, half = threadIdx.x >> 7;
    float acc[8] = {0,0,0,0,0,0,0,0};
    const float* W1p = ffw1 + col;
    for (int k4 = 0; k4 < 32; k4++) {
        float w0 = W1p[(4*k4+0)*H], w1 = W1p[(4*k4+1)*H], w2 = W1p[(4*k4+2)*H], w3 = W1p[(4*k4+3)*H];
        #pragma unroll
        for (int rr = 0; rr < 8; rr++) {
            float4 x4 = *(const float4*)&xs[half + rr*2][4*k4];
            acc[rr] = fmaf(x4.w, w3, fmaf(x4.z, w2, fmaf(x4.y, w1, fmaf(x4.x, w0, acc[rr]))));
        }
    }
    float b1 = ffb1[col];
    #pragma unroll
    for (int rr = 0; rr < 8; rr++) {
        float hv = acc[rr] + b1;
        hs[half + rr*2][col] = hv > 0.0f ? hv : 0.0f;
    }
    __syncthreads();
    #pragma unroll
    for (int rr = 0; rr < 8; rr++) acc[rr] = 0.0f;
    const float* W2p = ffw2 + col;
    for (int k4 = 0; k4 < 32; k4++) {
        float w0 = W2p[(4*k4+0)*H], w1 = W2p[(4*k4+1)*H], w2 = W2p[(4*k4+2)*H], w3 = W2p[(4*k4+3)*H];
        #pragma unroll
        for (int rr = 0; rr < 8; rr++) {
            float4 x4 = *(const float4*)&hs[half + rr*2][4*k4];
            acc[rr] = fmaf(x4.w, w3, fmaf(x4.z, w2, fmaf(x4.y, w1, fmaf(x4.x, w0, acc[rr]))));
        }
    }
    float b2 = ffb2[col];
    float* Z = ws + OFF_Z + g*R1*H;
    float ls = 0, lss = 0;
    #pragma unroll
    for (int rr = 0; rr < 8; rr++) {
        int row = rowbase + half + rr*2;
        float z = acc[rr] + b2 + xs[half + rr*2][col];
        Z[row*H + col] = z;
        ls += z; lss += z*z;
    }
    atomicAdd(&ws[ACC_FF + g*256 + col], ls);
    atomicAdd(&ws[ACC_FF + g*256 + 128 + col], lss);
}

// ---- final BN + output ----
__global__ __launch_bounds__(256) void k_f3(const float* __restrict__ bng, const float* __restrict__ bnb,
                                            float* __restrict__ ws, float* __restrict__ out) {
    int eidx = blockIdx.x * 256 + threadIdx.x;
    int g = eidx / (R1*H);
    int c = eidx & 127;
    float m = ws[ACC_FF + g*256 + c] / 1632.0f;
    float v = ws[ACC_FF + g*256 + 128 + c] / 1632.0f - m*m;
    float sc = bng[c] * rsqrtf(v + EPS);
    float sh = bnb[c] - m*sc;
    out[eidx] = ws[OFF_Z + eidx] * sc + sh;
}

extern "C" void kernel_launch(void* const* d_in, const int* in_sizes, int n_in,
                              void* d_out, int out_size, void* d_ws, size_t ws_size,
                              hipStream_t stream) {
    const float* x    = (const float*)d_in[0];
    const float* dm   = (const float*)d_in[1];
    const float* tw   = (const float*)d_in[2];
    const float* ead  = (const float*)d_in[3];
    const float* ear  = (const float*)d_in[4];
    const float* W0   = (const float*)d_in[5];
    const float* W1   = (const float*)d_in[6];
    const float* W2   = (const float*)d_in[7];
    const float* W3   = (const float*)d_in[8];
    const float* W4   = (const float*)d_in[9];
    const float* b0g  = (const float*)d_in[10];
    const float* b0b  = (const float*)d_in[11];
    const float* b1g  = (const float*)d_in[12];
    const float* b1b  = (const float*)d_in[13];
    const float* b2g  = (const float*)d_in[14];
    const float* b2b  = (const float*)d_in[15];
    const float* b3g  = (const float*)d_in[16];
    const float* b3b  = (const float*)d_in[17];
    const float* b4g  = (const float*)d_in[18];
    const float* b4b  = (const float*)d_in[19];
    const float* ffw1 = (const float*)d_in[20];
    const float* ffb1 = (const float*)d_in[21];
    const float* ffw2 = (const float*)d_in[22];
    const float* ffb2 = (const float*)d_in[23];
    const float* bng  = (const float*)d_in[24];
    const float* bnb  = (const float*)d_in[25];
    const float* Wvla = (const float*)d_in[26];
    const float* Wvlp = (const float*)d_in[27];
    const float* Wvld = (const float*)d_in[28];
    const float* Wga  = (const float*)d_in[29];
    const float* Wgp  = (const float*)d_in[30];
    const float* Wgd  = (const float*)d_in[31];
    const int* mask_d = (const int*)d_in[33];
    const int* mask_r = (const int*)d_in[34];
    float* ws = (float*)d_ws;
    float* out = (float*)d_out;

    k_zero    <<<1, 256, 0, stream>>>(ws);
    k_moments <<<256, 256, 0, stream>>>(ead, ear, ws);
    k_stpqr   <<<18, 128, 0, stream>>>(W3, W4, b3g, b3b, b4g, b4b, Wga, Wgp, Wgd, ws);
    k_nodeinit<<<102, 128, 0, stream>>>(x, dm, tw, W0, W1, W2, ws);
    k_nodenorm<<<102, 128, 0, stream>>>(b0g, b0b, b1g, b1b, b2g, b2b, ws);
    for (int l = 0; l < L; l++) {
        k_gemmVA<<<404, 256, 0, stream>>>(Wvla, Wvlp, Wvld, Wga, Wgp, Wgd, l, ws);
        k_attn  <<<dim3(8, 108), 256, 0, stream>>>(ead, ear, mask_d, mask_r, l, ws);
    }
    k_ff<<<204, 256, 0, stream>>>(ffw1, ffb1, ffw2, ffb2, ws);
    k_f3<<<1632, 256, 0, stream>>>(bng, bnb, ws, out);
}

// Round 10
// 327.442 us; speedup vs baseline: 1.9401x; 1.1229x over previous
//
#include <hip/hip_runtime.h>
#include <stdint.h>

#define B 16
#define D 2
#define NN 100
#define N2 50
#define NA 102
#define H 128
#define HE 64
#define L 3
#define SLOPE 0.2f
#define EPS 1e-5f

#define NAE (NA*NA)          // 10404
#define EN (B*NAE)           // 166464 edge rows per graph
#define R1 (B*NA)            // 1632
#define R2 (B*N2)            // 800
#define RV (R1 + 2*R2)       // 3232 rows in V/AB/XO per graph
#define NC 202               // per-batch row count in the reference's scrambled reshape
#define J 8                  // j-rows per attention block
#define TI 34                // i-tile rows staged in LDS

// ---- workspace layout (float offsets) ----
#define MOM_PART  0            // 2 graphs * 128 blocks * 5 partial moments = 1280
#define ACC_NODE  1408         // 3 segs * (128 sum + 128 sumsq) = 768
#define ACC_FF    2176         // 2 graphs * (128 sum + 128 sumsq) = 512
#define OFF_PQR   2816         // 18 * 384 = 6912 -> ends at 9728
#define OFF_X0    9728         // (round 9 bug: was 9472, overlapped PQR block 17)
#define OFF_V     (OFF_X0 + R1*H)
#define OFF_AB    (OFF_V + 2*RV*H)
#define OFF_XO    (OFF_AB + 2*RV*2*H)
#define OFF_Z     (OFF_XO + 2*RV*H)

// decode a V/AB/XO row index -> (batch, node)  [flat concat order: X1 | X2 | X3]
__device__ __forceinline__ void decode_vrow(int ridx, int& b, int& node) {
    if (ridx < R1) { b = ridx / NA; node = ridx % NA; }
    else if (ridx < R1 + R2) { int p = ridx - R1; b = p / N2; node = D + p % N2; }
    else { int p = ridx - R1 - R2; b = p / N2; node = D + N2 + p % N2; }
}
// decode node-init virtual row -> (batch, node); 32 dep / 800 pk / 800 dl
__device__ __forceinline__ void decode_nrow(int vr, int& b, int& node) {
    if (vr < 32) { b = vr >> 1; node = vr & 1; }
    else if (vr < 832) { int p = vr - 32; b = p / N2; node = D + p % N2; }
    else { int p = vr - 832; b = p / N2; node = D + N2 + p % N2; }
}
// conv output per the reference's EXACT (scrambled reshape) semantics:
// Xc[b,q] = flat[b*202+q], flat = [X1(1632); X2(800); X3(800)]
// out[b,n] = Xc[b,n] + (n>=D ? Xc[b,n+100] : 0)
__device__ __forceinline__ float combined(const float* __restrict__ XO, int b, int node, int k) {
    float v = XO[(b*NC + node)*H + k];
    if (node >= D) v += XO[(b*NC + node + 100)*H + k];
    return v;
}

// ---- edge-attr moments: per-block partial sums (no atomics, no pre-zero) ----
__global__ __launch_bounds__(256) void k_moments(const float* __restrict__ ea_d,
                                                 const float* __restrict__ ea_r,
                                                 float* __restrict__ ws) {
    int g = blockIdx.x >> 7;
    int bb = blockIdx.x & 127;
    const float2* ea = (const float2*)(g ? ea_r : ea_d);
    float s0 = 0, s1 = 0, s00 = 0, s11 = 0, s01 = 0;
    for (int idx = bb*256 + threadIdx.x; idx < EN; idx += 128*256) {
        float2 v = ea[idx];
        s0 += v.x; s1 += v.y; s00 += v.x*v.x; s11 += v.y*v.y; s01 += v.x*v.y;
    }
    __shared__ float sd[256];
    float vals[5] = {s0, s1, s00, s11, s01};
    for (int q = 0; q < 5; q++) {
        sd[threadIdx.x] = vals[q];
        __syncthreads();
        for (int off = 128; off > 0; off >>= 1) {
            if (threadIdx.x < off) sd[threadIdx.x] += sd[threadIdx.x + off];
            __syncthreads();
        }
        if (threadIdx.x == 0) ws[MOM_PART + (g*128 + bb)*5 + q] = sd[0];
        __syncthreads();
    }
}

// ---- reduce moments, fold edge BN + we into P/Q/R; block 0 zeros accumulators ----
__global__ __launch_bounds__(128) void k_stpqr(const float* __restrict__ W3, const float* __restrict__ W4,
                                               const float* __restrict__ b3g, const float* __restrict__ b3b,
                                               const float* __restrict__ b4g, const float* __restrict__ b4b,
                                               const float* __restrict__ Wga, const float* __restrict__ Wgp,
                                               const float* __restrict__ Wgd, float* __restrict__ ws) {
    int bx = blockIdx.x;           // 18 = 2 graphs * 3 segs * 3 layers
    int g = bx / 9, rem = bx % 9, seg = rem / 3, l = rem % 3;
    int t = threadIdx.x;
    if (bx == 0) {                  // zero ACC_NODE + ACC_FF (1280 floats)
        for (int i = t; i < 1280; i += 128) ws[ACC_NODE + i] = 0.0f;
    }
    __shared__ float momsh[5];
    __shared__ float st[192];
    if (t < 5) {
        float s = 0;
        for (int p = 0; p < 128; p++) s += ws[MOM_PART + (g*128 + p)*5 + t];
        momsh[t] = s;
    }
    __syncthreads();
    if (t < 64) {
        const float* W  = g ? W4 : W3;
        const float* gv = g ? b4g : b3g;
        const float* bv = g ? b4b : b3b;
        float Nr = (float)EN;
        float S0 = momsh[0], S1 = momsh[1], S00 = momsh[2], S11 = momsh[3], S01 = momsh[4];
        float w0 = W[t], w1 = W[64 + t];
        float m = (S0*w0 + S1*w1) / Nr;
        float E2 = (S00*w0*w0 + 2.0f*S01*w0*w1 + S11*w1*w1) / Nr;
        float var = E2 - m*m;
        float s = gv[t] * rsqrtf(var + EPS);
        st[t] = w0 * s; st[64 + t] = w1 * s; st[128 + t] = bv[t] - m*s;
    }
    __syncthreads();
    int h = t;
    const float* Wg = (seg == 0 ? Wga : (seg == 1 ? Wgp : Wgd)) + l*320*H;
    float P = 0, Q = 0, Rr = 0;
    for (int cc = 0; cc < HE; cc++) {
        float w = Wg[(2*H + cc)*H + h];
        P += st[cc]*w; Q += st[64 + cc]*w; Rr += st[128 + cc]*w;
    }
    float* o = ws + OFF_PQR + ((g*3 + seg)*3 + l)*384;
    o[h] = P; o[128 + h] = Q; o[256 + h] = Rr;
}

// ---- initial node embeddings ----
__global__ __launch_bounds__(128) void k_nodeinit(const float* __restrict__ x, const float* __restrict__ dm,
                                                  const float* __restrict__ tw,
                                                  const float* __restrict__ W0, const float* __restrict__ W1,
                                                  const float* __restrict__ W2, float* __restrict__ ws) {
    int c = threadIdx.x, bx = blockIdx.x;
    int seg = (bx < 2) ? 0 : (bx < 52 ? 1 : 2);
    const float* W = seg == 0 ? W0 : (seg == 1 ? W1 : W2);
    int nf = seg == 1 ? 10 : 5;
    float w[10];
    for (int f = 0; f < nf; f++) w[f] = W[f*H + c];
    float* x0 = ws + OFF_X0;
    float ls = 0, lss = 0;
    for (int r = 0; r < 16; r++) {
        int vr = bx*16 + r;
        int b, node; decode_nrow(vr, b, node);
        int row = b*NA + node;
        float y = x[row*2]*w[0] + x[row*2+1]*w[1] + dm[row]*w[2]
                + tw[row*2]*w[3] + tw[row*2+1]*w[4];
        if (seg == 1) {
            int r2 = row + N2;
            y += x[r2*2]*w[5] + x[r2*2+1]*w[6] + dm[r2]*w[7]
               + tw[r2*2]*w[8] + tw[r2*2+1]*w[9];
        }
        x0[row*H + c] = y;
        ls += y; lss += y*y;
    }
    atomicAdd(&ws[ACC_NODE + seg*256 + c], ls);
    atomicAdd(&ws[ACC_NODE + seg*256 + 128 + c], lss);
}

__global__ __launch_bounds__(128) void k_nodenorm(const float* __restrict__ b0g, const float* __restrict__ b0b,
                                                  const float* __restrict__ b1g, const float* __restrict__ b1b,
                                                  const float* __restrict__ b2g, const float* __restrict__ b2b,
                                                  float* __restrict__ ws) {
    int c = threadIdx.x, bx = blockIdx.x;
    int seg = (bx < 2) ? 0 : (bx < 52 ? 1 : 2);
    float cnt = seg == 0 ? 32.0f : 800.0f;
    float m = ws[ACC_NODE + seg*256 + c] / cnt;
    float v = ws[ACC_NODE + seg*256 + 128 + c] / cnt - m*m;
    const float* gp = seg == 0 ? b0g : (seg == 1 ? b1g : b2g);
    const float* bp = seg == 0 ? b0b : (seg == 1 ? b1b : b2b);
    float sc = gp[c] * rsqrtf(v + EPS);
    float sh = bp[c] - m*sc;
    float* x0 = ws + OFF_X0;
    for (int r = 0; r < 16; r++) {
        int vr = bx*16 + r;
        int b, node; decode_nrow(vr, b, node);
        int row = b*NA + node;
        x0[row*H + c] = x0[row*H + c]*sc + sh;
    }
}

// ---- fused GEMM, 8-row tiles, weight double-buffer ----
__global__ __launch_bounds__(256) void k_gemmVA(const float* __restrict__ Wvla, const float* __restrict__ Wvlp,
                                                const float* __restrict__ Wvld,
                                                const float* __restrict__ Wga, const float* __restrict__ Wgp,
                                                const float* __restrict__ Wgd,
                                                int layer, float* __restrict__ ws) {
    __shared__ float xs[8][H];
    __shared__ float vs[8][H];
    int g = blockIdx.x / 404, tb = blockIdx.x % 404;
    int rowbase = tb * 8;
    const float* x0 = ws + OFF_X0;
    const float* XO = ws + OFF_XO + g*RV*H;
    for (int e = 0; e < 4; e++) {
        int lin = threadIdx.x + e*256;
        int r = lin >> 7, k = lin & 127;
        int b, node; decode_vrow(rowbase + r, b, node);
        xs[r][k] = (layer == 0) ? x0[(b*NA + node)*H + k] : combined(XO, b, node, k);
    }
    __syncthreads();
    int seg = tb < 204 ? 0 : (tb < 304 ? 1 : 2);
    const float* W = (seg == 0 ? Wvla : (seg == 1 ? Wvlp : Wvld)) + layer*H*H;
    int col = threadIdx.x & 127, half = threadIdx.x >> 7;
    float acc[4] = {0,0,0,0};
    const float* Wp = W + col;
    float w0 = Wp[0], w1 = Wp[H], w2 = Wp[2*H], w3 = Wp[3*H];
    for (int k4 = 0; k4 < 32; k4++) {
        int kn = ((k4 + 1) & 31) * 4;
        const float* q = Wp + kn*H;
        float n0 = q[0], n1 = q[H], n2 = q[2*H], n3 = q[3*H];
        #pragma unroll
        for (int rr = 0; rr < 4; rr++) {
            float4 x4 = *(const float4*)&xs[half + rr*2][4*k4];
            acc[rr] = fmaf(x4.w, w3, fmaf(x4.z, w2, fmaf(x4.y, w1, fmaf(x4.x, w0, acc[rr]))));
        }
        w0 = n0; w1 = n1; w2 = n2; w3 = n3;
    }
    float* V = ws + OFF_V + g*RV*H;
    #pragma unroll
    for (int rr = 0; rr < 4; rr++) {
        vs[half + rr*2][col] = acc[rr];
        V[(rowbase + half + rr*2)*H + col] = acc[rr];
    }
    __syncthreads();
    const float* Wg = (seg == 0 ? Wga : (seg == 1 ? Wgp : Wgd)) + layer*320*H;
    int c = threadIdx.x;
    const float* wb = Wg + ((c >> 7) * H) * H + (c & 127);
    float a2[8];
    #pragma unroll
    for (int rr = 0; rr < 8; rr++) a2[rr] = 0.0f;
    float v0 = wb[0], v1 = wb[H], v2 = wb[2*H], v3 = wb[3*H];
    for (int k4 = 0; k4 < 32; k4++) {
        int kn = ((k4 + 1) & 31) * 4;
        const float* q = wb + kn*H;
        float n0 = q[0], n1 = q[H], n2 = q[2*H], n3 = q[3*H];
        #pragma unroll
        for (int rr = 0; rr < 8; rr++) {
            float4 x4 = *(const float4*)&vs[rr][4*k4];
            a2[rr] = fmaf(x4.w, v3, fmaf(x4.z, v2, fmaf(x4.y, v1, fmaf(x4.x, v0, a2[rr]))));
        }
        v0 = n0; v1 = n1; v2 = n2; v3 = n3;
    }
    float* AB = ws + OFF_AB + g*RV*2*H;
    #pragma unroll
    for (int rr = 0; rr < 8; rr++) AB[(rowbase + rr)*256 + c] = a2[rr];
}

// ---- fused attention v5: 512 thr = 4 j-pairs x 2 i-halves, LDS-tiled, XCD swizzle ----
__global__ __launch_bounds__(512) void k_attn(const float* __restrict__ ea_d, const float* __restrict__ ea_r,
                                              const int* __restrict__ mask_d, const int* __restrict__ mask_r,
                                              int layer, float* __restrict__ ws) {
    int k = blockIdx.x, y = blockIdx.y;
    int ci = y / 27, r = y % 27;
    int combo = k + 8*ci;            // 0..31
    int g = combo >> 4, b = combo & 15;
    int seg, jg, n, o, base;
    if (r < 13)      { seg = 0; jg = r;      n = NA; o = 0;      base = 0; }
    else if (r < 20) { seg = 1; jg = r - 13; n = N2; o = D;      base = R1; }
    else             { seg = 2; jg = r - 20; n = N2; o = D + N2; base = R1 + R2; }
    int j0 = jg * J;
    int jc = min(J, n - j0);
    int tid = threadIdx.x;
    int c = tid & 63, wv = tid >> 6;          // wave id 0..7
    int pair = wv & 3, ihalf = wv >> 2;
    int jj0 = 2*pair, jj1 = 2*pair + 1;

    const float* pqr = ws + OFF_PQR + ((g*3 + seg)*3 + layer)*384;
    float2 Pv = ((const float2*)pqr)[c];
    float2 Qv = ((const float2*)(pqr + 128))[c];
    float2 Rv = ((const float2*)(pqr + 256))[c];
    const float2* ea = (const float2*)(g ? ea_r : ea_d);
    const int* mask = g ? mask_r : mask_d;
    const float* V  = ws + OFF_V  + g*RV*H   + base*H;
    const float* AB = ws + OFF_AB + g*RV*2*H + base*2*H;

    __shared__ float2 Bs[TI][64];
    __shared__ float2 Vs[TI][64];
    __shared__ float2 se[J][104];
    __shared__ int    msk_s[104];

    if (tid < n) {
        int ibase = b*NAE + (o + tid)*NA + o + j0;
        int bits = 0;
        #pragma unroll
        for (int jj = 0; jj < J; jj++) {
            int valid = (jj < jc) ? (mask[ibase + jj] != 0) : 0;
            bits |= valid << jj;
            se[jj][tid] = valid ? ea[ibase + jj] : make_float2(0.f, 0.f);
        }
        msk_s[tid] = bits;
    }

    float2 Aj0 = make_float2(0.f, 0.f), Aj1 = make_float2(0.f, 0.f);
    if (jj0 < jc) Aj0 = *(const float2*)&AB[(b*n + j0 + jj0)*256 + 2*c];
    if (jj1 < jc) Aj1 = *(const float2*)&AB[(b*n + j0 + jj1)*256 + 2*c];
    float A0x = Aj0.x + Rv.x, A0y = Aj0.y + Rv.y;
    float A1x = Aj1.x + Rv.x, A1y = Aj1.y + Rv.y;
    float2 l0 = make_float2(0.f, 0.f), a0 = make_float2(0.f, 0.f);
    float2 l1 = make_float2(0.f, 0.f), a1 = make_float2(0.f, 0.f);

    int nh = (n + 1) >> 1;
    int i0w = ihalf ? nh : 0;
    int i1w = ihalf ? n : nh;

    for (int t0 = 0; t0 < n; t0 += TI) {
        int rows = min(TI, n - t0);
        __syncthreads();                       // prev tile consumed (stage visible on 1st iter)
        for (int idx = tid; idx < rows*64; idx += 512) {
            int ir = idx >> 6, cc = idx & 63;
            int gi = b*n + t0 + ir;
            Bs[ir][cc] = *(const float2*)&AB[gi*256 + 128 + 2*cc];
            Vs[ir][cc] = *(const float2*)&V[gi*128 + 2*cc];
        }
        __syncthreads();
        int irlo = max(0, i0w - t0);
        int irhi = min(rows, i1w - t0);
        for (int ir = irlo; ir < irhi; ir++) {
            int i = t0 + ir;
            int bits = msk_s[i];
            if (!(bits & ((1<<jj0) | (1<<jj1)))) continue;
            float2 Bi = Bs[ir][c];
            float2 Vi = Vs[ir][c];
            if (bits & (1<<jj0)) {
                float2 ev = se[jj0][i];
                float tx = fmaf(ev.x, Pv.x, fmaf(ev.y, Qv.x, A0x + Bi.x));
                float ty = fmaf(ev.x, Pv.y, fmaf(ev.y, Qv.y, A0y + Bi.y));
                tx = fminf(fmaxf(tx, SLOPE*tx), 80.0f);
                ty = fminf(fmaxf(ty, SLOPE*ty), 80.0f);
                float px = __expf(tx), py = __expf(ty);
                l0.x += px; l0.y += py;
                a0.x = fmaf(px, Vi.x, a0.x); a0.y = fmaf(py, Vi.y, a0.y);
            }
            if (bits & (1<<jj1)) {
                float2 ev = se[jj1][i];
                float tx = fmaf(ev.x, Pv.x, fmaf(ev.y, Qv.x, A1x + Bi.x));
                float ty = fmaf(ev.x, Pv.y, fmaf(ev.y, Qv.y, A1y + Bi.y));
                tx = fminf(fmaxf(tx, SLOPE*tx), 80.0f);
                ty = fminf(fmaxf(ty, SLOPE*ty), 80.0f);
                float px = __expf(tx), py = __expf(ty);
                l1.x += px; l1.y += py;
                a1.x = fmaf(px, Vi.x, a1.x); a1.y = fmaf(py, Vi.y, a1.y);
            }
        }
    }
    // merge the two i-halves (conflict-free: mg[k][pair][c])
    __syncthreads();
    float* mg = (float*)Bs;                    // 8*4*64 floats = 8 KiB, fits in Bs
    if (ihalf == 1) {
        mg[(0*4 + pair)*64 + c] = l0.x;  mg[(1*4 + pair)*64 + c] = l0.y;
        mg[(2*4 + pair)*64 + c] = l1.x;  mg[(3*4 + pair)*64 + c] = l1.y;
        mg[(4*4 + pair)*64 + c] = a0.x;  mg[(5*4 + pair)*64 + c] = a0.y;
        mg[(6*4 + pair)*64 + c] = a1.x;  mg[(7*4 + pair)*64 + c] = a1.y;
    }
    __syncthreads();
    if (ihalf == 0) {
        l0.x += mg[(0*4 + pair)*64 + c];  l0.y += mg[(1*4 + pair)*64 + c];
        l1.x += mg[(2*4 + pair)*64 + c];  l1.y += mg[(3*4 + pair)*64 + c];
        a0.x += mg[(4*4 + pair)*64 + c];  a0.y += mg[(5*4 + pair)*64 + c];
        a1.x += mg[(6*4 + pair)*64 + c];  a1.y += mg[(7*4 + pair)*64 + c];
        float* XO = ws + OFF_XO + g*RV*H + base*H;
        if (jj0 < jc)
            ((float2*)&XO[(b*n + j0 + jj0)*H])[c] = make_float2(a0.x/l0.x, a0.y/l0.y);
        if (jj1 < jc)
            ((float2*)&XO[(b*n + j0 + jj1)*H])[c] = make_float2(a1.x/l1.x, a1.y/l1.y);
    }
}

// ---- fused feed-forward, 8-row tiles, weight double-buffer ----
__global__ __launch_bounds__(256) void k_ff(const float* __restrict__ ffw1, const float* __restrict__ ffb1,
                                            const float* __restrict__ ffw2, const float* __restrict__ ffb2,
                                            float* __restrict__ ws) {
    __shared__ float xs[8][H];
    __shared__ float hs[8][H];
    int g = blockIdx.x / 204, tb = blockIdx.x % 204;
    int rowbase = tb * 8;
    const float* XO = ws + OFF_XO + g*RV*H;
    for (int e = 0; e < 4; e++) {
        int lin = threadIdx.x + e*256;
        int r = lin >> 7, k = lin & 127;
        int ridx = rowbase + r;
        int b = ridx / NA, node = ridx % NA;
        xs[r][k] = combined(XO, b, node, k);
    }
    __syncthreads();
    int col = threadIdx.x & 127, half = threadIdx.x >> 7;
    float acc[4] = {0,0,0,0};
    const float* W1p = ffw1 + col;
    float w0 = W1p[0], w1 = W1p[H], w2 = W1p[2*H], w3 = W1p[3*H];
    for (int k4 = 0; k4 < 32; k4++) {
        int kn = ((k4 + 1) & 31) * 4;
        const float* q = W1p + kn*H;
        float n0 = q[0], n1 = q[H], n2 = q[2*H], n3 = q[3*H];
        #pragma unroll
        for (int rr = 0; rr < 4; rr++) {
            float4 x4 = *(const float4*)&xs[half + rr*2][4*k4];
            acc[rr] = fmaf(x4.w, w3, fmaf(x4.z, w2, fmaf(x4.y, w1, fmaf(x4.x, w0, acc[rr]))));
        }
        w0 = n0; w1 = n1; w2 = n2; w3 = n3;
    }
    float b1 = ffb1[col];
    #pragma unroll
    for (int rr = 0; rr < 4; rr++) {
        float hv = acc[rr] + b1;
        hs[half + rr*2][col] = hv > 0.0f ? hv : 0.0f;
    }
    __syncthreads();
    #pragma unroll
    for (int rr = 0; rr < 4; rr++) acc[rr] = 0.0f;
    const float* W2p = ffw2 + col;
    w0 = W2p[0]; w1 = W2p[H]; w2 = W2p[2*H]; w3 = W2p[3*H];
    for (int k4 = 0; k4 < 32; k4++) {
        int kn = ((k4 + 1) & 31) * 4;
        const float* q = W2p + kn*H;
        float n0 = q[0], n1 = q[H], n2 = q[2*H], n3 = q[3*H];
        #pragma unroll
        for (int rr = 0; rr < 4; rr++) {
            float4 x4 = *(const float4*)&hs[half + rr*2][4*k4];
            acc[rr] = fmaf(x4.w, w3, fmaf(x4.z, w2, fmaf(x4.y, w1, fmaf(x4.x, w0, acc[rr]))));
        }
        w0 = n0; w1 = n1; w2 = n2; w3 = n3;
    }
    float b2 = ffb2[col];
    float* Z = ws + OFF_Z + g*R1*H;
    float ls = 0, lss = 0;
    #pragma unroll
    for (int rr = 0; rr < 4; rr++) {
        int row = rowbase + half + rr*2;
        float z = acc[rr] + b2 + xs[half + rr*2][col];
        Z[row*H + col] = z;
        ls += z; lss += z*z;
    }
    atomicAdd(&ws[ACC_FF + g*256 + col], ls);
    atomicAdd(&ws[ACC_FF + g*256 + 128 + col], lss);
}

// ---- final BN + output ----
__global__ __launch_bounds__(256) void k_f3(const float* __restrict__ bng, const float* __restrict__ bnb,
                                            float* __restrict__ ws, float* __restrict__ out) {
    int eidx = blockIdx.x * 256 + threadIdx.x;
    int g = eidx / (R1*H);
    int c = eidx & 127;
    float m = ws[ACC_FF + g*256 + c] / 1632.0f;
    float v = ws[ACC_FF + g*256 + 128 + c] / 1632.0f - m*m;
    float sc = bng[c] * rsqrtf(v + EPS);
    float sh = bnb[c] - m*sc;
    out[eidx] = ws[OFF_Z + eidx] * sc + sh;
}

extern "C" void kernel_launch(void* const* d_in, const int* in_sizes, int n_in,
                              void* d_out, int out_size, void* d_ws, size_t ws_size,
                              hipStream_t stream) {
    const float* x    = (const float*)d_in[0];
    const float* dm   = (const float*)d_in[1];
    const float* tw   = (const float*)d_in[2];
    const float* ead  = (const float*)d_in[3];
    const float* ear  = (const float*)d_in[4];
    const float* W0   = (const float*)d_in[5];
    const float* W1   = (const float*)d_in[6];
    const float* W2   = (const float*)d_in[7];
    const float* W3   = (const float*)d_in[8];
    const float* W4   = (const float*)d_in[9];
    const float* b0g  = (const float*)d_in[10];
    const float* b0b  = (const float*)d_in[11];
    const float* b1g  = (const float*)d_in[12];
    const float* b1b  = (const float*)d_in[13];
    const float* b2g  = (const float*)d_in[14];
    const float* b2b  = (const float*)d_in[15];
    const float* b3g  = (const float*)d_in[16];
    const float* b3b  = (const float*)d_in[17];
    const float* b4g  = (const float*)d_in[18];
    const float* b4b  = (const float*)d_in[19];
    const float* ffw1 = (const float*)d_in[20];
    const float* ffb1 = (const float*)d_in[21];
    const float* ffw2 = (const float*)d_in[22];
    const float* ffb2 = (const float*)d_in[23];
    const float* bng  = (const float*)d_in[24];
    const float* bnb  = (const float*)d_in[25];
    const float* Wvla = (const float*)d_in[26];
    const float* Wvlp = (const float*)d_in[27];
    const float* Wvld = (const float*)d_in[28];
    const float* Wga  = (const float*)d_in[29];
    const float* Wgp  = (const float*)d_in[30];
    const float* Wgd  = (const float*)d_in[31];
    const int* mask_d = (const int*)d_in[33];
    const int* mask_r = (const int*)d_in[34];
    float* ws = (float*)d_ws;
    float* out = (float*)d_out;

    k_moments <<<256, 256, 0, stream>>>(ead, ear, ws);
    k_stpqr   <<<18, 128, 0, stream>>>(W3, W4, b3g, b3b, b4g, b4b, Wga, Wgp, Wgd, ws);
    k_nodeinit<<<102, 128, 0, stream>>>(x, dm, tw, W0, W1, W2, ws);
    k_nodenorm<<<102, 128, 0, stream>>>(b0g, b0b, b1g, b1b, b2g, b2b, ws);
    for (int l = 0; l < L; l++) {
        k_gemmVA<<<808, 256, 0, stream>>>(Wvla, Wvlp, Wvld, Wga, Wgp, Wgd, l, ws);
        k_attn  <<<dim3(8, 108), 512, 0, stream>>>(ead, ear, mask_d, mask_r, l, ws);
    }
    k_ff<<<408, 256, 0, stream>>>(ffw1, ffb1, ffw2, ffb2, ws);
    k_f3<<<1632, 256, 0, stream>>>(bng, bnb, ws, out);
}